// Round 6
// baseline (228.859 us; speedup 1.0000x reference)
//
#include <hip/hip_runtime.h>
#include <math.h>

// ---------------------------------------------------------------------------
// TransNeXt aggregated attention. Round 17:
//  - x-GEMM and proj -> <128,128> tiles WITH the counted-vmcnt pipeline
//    (R13's tile + R14's schedule): halves LDS bytes/FLOP (the <128,64>
//    K-step was ~288cyc LDS vs ~38cyc MFMA per block) and halves B-panel
//    L2 refetch. 1024 blocks = 4/CU exact at 32KB LDS.
//  - attn bias gather de-fattened: rpi packed to ushort in prep (halves
//    index FETCH), cpb MLP writes transposed per-head fp16 table cpbT[h][T]
//    (10KB/head, L1-resident 2B gathers instead of 4B stride-8 from 32KB).
//  6 dispatches.
// B=4, H=W=64, C=256, NH=8, hd=32, LOCAL_LEN=9, pool 8x8=64
// ---------------------------------------------------------------------------

typedef unsigned short ushort_t;
typedef __attribute__((ext_vector_type(8))) _Float16 half8;
typedef __attribute__((ext_vector_type(2))) _Float16 half2_t;
typedef __attribute__((ext_vector_type(4))) float f32x4;
typedef __attribute__((ext_vector_type(4))) int int4_t;

static __device__ __forceinline__ ushort_t f2h(float f) {
    _Float16 h = (_Float16)f;           // RTNE
    return *(ushort_t*)&h;
}

static __device__ __forceinline__ float fdot2f(half2_t a, half2_t b, float c) {
#if __has_builtin(__builtin_amdgcn_fdot2)
    return __builtin_amdgcn_fdot2(a, b, c, false);
#else
    return (float)a[0] * (float)b[0] + (float)a[1] * (float)b[1] + c;
#endif
}

// ---- DPP lane reductions (VALU pipe) --------------------------------------
template <int CTRL>
static __device__ __forceinline__ float dpp_addf(float x) {
    int v = __builtin_amdgcn_update_dpp(
        0, __builtin_bit_cast(int, x), CTRL, 0xF, 0xF, true);
    return x + __builtin_bit_cast(float, v);
}
template <int CTRL>
static __device__ __forceinline__ float dpp_maxf(float x) {
    int v = __builtin_amdgcn_update_dpp(
        0, __builtin_bit_cast(int, x), CTRL, 0xF, 0xF, true);
    return fmaxf(x, __builtin_bit_cast(float, v));
}
static __device__ __forceinline__ float quad_sumf(float x) {
    return dpp_addf<0x4E>(dpp_addf<0xB1>(x));
}
static __device__ __forceinline__ float sum16f(float x) {
    return dpp_addf<0x128>(dpp_addf<0x124>(quad_sumf(x)));
}
static __device__ __forceinline__ float max16f(float x) {
    return dpp_maxf<0x128>(dpp_maxf<0x124>(dpp_maxf<0x4E>(dpp_maxf<0xB1>(x))));
}

#define GLOAD16(g, l)                                                        \
    __builtin_amdgcn_global_load_lds(                                        \
        (const __attribute__((address_space(1))) unsigned int*)(g),          \
        (__attribute__((address_space(3))) unsigned int*)(l), 16, 0, 0)

// ---------------------------------------------------------------------------
// mfma_hgemm<TM,TN,AHM>: C = A @ W^T + bias, fp16 in, fp32 accum.
// 4 waves 2x2; depth-2 counted-vmcnt pipeline; LDS XOR-swizzle.
// AHM: A is head-major (8, Arows, 32) -- one head per BK=32 K-step.
// mode 0: qh (8,M,32) | kvh k normed (8,M,64) | kvh v | gelu -> xsrh (M,256)
// mode 1 (proj, N=256): out0 fp32 (M,256)
// mode 2 (kv_p, N=512): kvph (8,Arows,64), k normed
// ---------------------------------------------------------------------------
template <int TM, int TN, bool AHM>
__global__ __launch_bounds__(256) void mfma_hgemm(
    const ushort_t* __restrict__ Ag, const ushort_t* __restrict__ Bg,
    const float* __restrict__ bias, float* __restrict__ out0,
    ushort_t* __restrict__ qh_out, ushort_t* __restrict__ kvh,
    ushort_t* __restrict__ xsrh, int mode, int Arows)
{
    const int K = 256;
    const int IM = TM / 32;
    const int JN = TN / 32;
    constexpr int LPS = TM / 64 + TN / 64;
    __shared__ ushort_t Ah[2][TM * 32];
    __shared__ ushort_t Bh[2][TN * 32];

    const int t = threadIdx.x;
    const int w = t >> 6;
    const int lane = t & 63;

    // XCD-aware bijective chunk swizzle (all grids are %8 == 0)
    const int nwg = gridDim.x * gridDim.y;
    int wg = blockIdx.y * gridDim.x + blockIdx.x;
    wg = (wg & 7) * (nwg >> 3) + (wg >> 3);
    const int bm = (wg / gridDim.x) * TM;
    const int bn = (wg % gridDim.x) * TN;

    const int wm = (w >> 1) * (TM / 2);
    const int wn = (w & 1) * (TN / 2);

    f32x4 acc[IM][JN];
#pragma unroll
    for (int i = 0; i < IM; ++i)
#pragma unroll
        for (int j = 0; j < JN; ++j) acc[i][j] = f32x4{0.f, 0.f, 0.f, 0.f};

    const int lrow  = t >> 2;
    const int lk8sw = ((t & 3) ^ ((t >> 3) & 3)) * 8;  // pre-swizzled src col

#define STAGE(bufi, k0s)                                                     \
    do {                                                                     \
        _Pragma("unroll")                                                    \
        for (int r = 0; r < TM / 64; ++r) {                                  \
            const ushort_t* srcA = AHM                                       \
                ? Ag + ((size_t)((k0s) >> 5) * Arows + (bm + r * 64 + lrow)) * 32 + lk8sw \
                : Ag + (size_t)(bm + r * 64 + lrow) * K + (k0s) + lk8sw;     \
            GLOAD16(srcA, &Ah[bufi][(unsigned)(r * 64 + w * 16) * 32]);      \
        }                                                                    \
        _Pragma("unroll")                                                    \
        for (int r = 0; r < TN / 64; ++r)                                    \
            GLOAD16(Bg + (size_t)(bn + r * 64 + lrow) * K + (k0s) + lk8sw,   \
                    &Bh[bufi][(unsigned)(r * 64 + w * 16) * 32]);            \
    } while (0)

    const int fr   = lane & 15;
    const int sws8 = ((lane >> 4) ^ ((fr >> 1) & 3)) * 8;  // swizzled read slot

#define COMPUTE(bufi)                                                        \
    do {                                                                     \
        half8 af[IM], bf[JN];                                                \
        _Pragma("unroll")                                                    \
        for (int i2 = 0; i2 < IM; ++i2)                                      \
            af[i2] = *(const half8*)&Ah[bufi][(unsigned)(wm + i2 * 16 + fr) * 32 + sws8]; \
        _Pragma("unroll")                                                    \
        for (int j2 = 0; j2 < JN; ++j2)                                      \
            bf[j2] = *(const half8*)&Bh[bufi][(unsigned)(wn + j2 * 16 + fr) * 32 + sws8]; \
        __builtin_amdgcn_s_setprio(1);                                       \
        _Pragma("unroll")                                                    \
        for (int i2 = 0; i2 < IM; ++i2)                                      \
            _Pragma("unroll")                                                \
            for (int j2 = 0; j2 < JN; ++j2)                                  \
                acc[i2][j2] = __builtin_amdgcn_mfma_f32_16x16x32_f16(        \
                    af[i2], bf[j2], acc[i2][j2], 0, 0, 0);                   \
        __builtin_amdgcn_s_setprio(0);                                       \
    } while (0)

    STAGE(0, 0);
    STAGE(1, 32);
    int buf = 0;
#pragma unroll
    for (int s = 0; s < K / 32 - 1; ++s) {
        asm volatile("s_waitcnt vmcnt(%0)" :: "n"(LPS) : "memory");
        __builtin_amdgcn_s_barrier();
        asm volatile("" ::: "memory");
        COMPUTE(buf);
        asm volatile("" ::: "memory");
        __builtin_amdgcn_s_barrier();
        asm volatile("" ::: "memory");
        if (s + 2 < K / 32) STAGE(buf, (s + 2) * 32);
        buf ^= 1;
    }
    asm volatile("s_waitcnt vmcnt(0)" ::: "memory");
    __builtin_amdgcn_s_barrier();
    asm volatile("" ::: "memory");
    COMPUTE(buf);
#undef COMPUTE
#undef STAGE

    // epilogue: C/D layout col=lane&15, row=(lane>>4)*4+reg.
    const int q4 = (lane >> 4) * 4;
#pragma unroll
    for (int i = 0; i < IM; ++i) {
#pragma unroll
        for (int jp = 0; jp < JN / 2; ++jp) {
#pragma unroll
            for (int r = 0; r < 4; ++r) {
                const int row = bm + wm + i * 16 + q4 + r;
                const int col0 = bn + wn + jp * 32 + fr;
                const int col1 = col0 + 16;
                float v0 = acc[i][2 * jp][r] + bias[col0];
                float v1 = acc[i][2 * jp + 1][r] + bias[col1];
                if (mode == 0) {
                    if (col0 < 256) {
                        const size_t base = ((size_t)(col0 >> 5) * Arows + row) * 32;
                        qh_out[base + fr]      = f2h(v0);
                        qh_out[base + fr + 16] = f2h(v1);
                    } else if (col0 < 512) {   // k: fused per-head L2 norm
                        const float ss = sum16f(v0 * v0 + v1 * v1);
                        const float invn = 1.0f / fmaxf(sqrtf(ss), 1e-12f);
                        const size_t base = ((size_t)((col0 - 256) >> 5) * Arows + row) * 64;
                        kvh[base + fr]      = f2h(v0 * invn);
                        kvh[base + fr + 16] = f2h(v1 * invn);
                    } else if (col0 < 768) {   // v
                        const size_t base = ((size_t)((col0 - 512) >> 5) * Arows + row) * 64 + 32;
                        kvh[base + fr]      = f2h(v0);
                        kvh[base + fr + 16] = f2h(v1);
                    } else {                    // sr + gelu (row-major kept)
                        v0 = 0.5f * v0 * (1.0f + erff(v0 * 0.70710678118654752f));
                        v1 = 0.5f * v1 * (1.0f + erff(v1 * 0.70710678118654752f));
                        xsrh[(size_t)row * 256 + (col0 - 768)] = f2h(v0);
                        xsrh[(size_t)row * 256 + (col1 - 768)] = f2h(v1);
                    }
                } else if (mode == 2) {         // kv_p head-major
                    if (col0 < 256) {           // k_pool: fused per-head norm
                        const float ss = sum16f(v0 * v0 + v1 * v1);
                        const float invn = 1.0f / fmaxf(sqrtf(ss), 1e-12f);
                        const size_t base = ((size_t)(col0 >> 5) * Arows + row) * 64;
                        kvh[base + fr]      = f2h(v0 * invn);
                        kvh[base + fr + 16] = f2h(v1 * invn);
                    } else {
                        const size_t base = ((size_t)((col0 - 256) >> 5) * Arows + row) * 64 + 32;
                        kvh[base + fr]      = f2h(v0);
                        kvh[base + fr + 16] = f2h(v1);
                    }
                } else {
                    out0[(size_t)row * 256 + col0] = v0;
                    out0[(size_t)row * 256 + col1] = v1;
                }
            }
        }
    }
}

// prep_cpb: x cast + weight/bias packing + rpi->ushort + cpb MLP (fp16,
// transposed per-head) in one kernel.
__global__ __launch_bounds__(256) void prep_cpb(
    const float4* __restrict__ x, ushort4* __restrict__ xh, int n4, int nprep,
    const float* __restrict__ qw, const float* __restrict__ kvw,
    const float* __restrict__ srw, const float* __restrict__ pw,
    const float* __restrict__ qb, const float* __restrict__ kvb,
    const float* __restrict__ srb,
    const int* __restrict__ rpi, ushort_t* __restrict__ rpi16,
    ushort_t* __restrict__ Wall, ushort_t* __restrict__ Pw,
    float* __restrict__ ball,
    const float* __restrict__ table, const float* __restrict__ w1,
    const float* __restrict__ b1, const float* __restrict__ w2,
    const float* __restrict__ b2, ushort_t* __restrict__ cpbT, int T)
{
    if (blockIdx.x >= nprep) {
        const int wv = threadIdx.x >> 6;
        const int lane = threadIdx.x & 63;
        const int row = (blockIdx.x - nprep) * 4 + wv;
        if (row >= T) return;
        const float t0 = table[(size_t)row * 2];
        const float t1 = table[(size_t)row * 2 + 1];
        const int base = lane * 8;

        const float4* w1p = (const float4*)(w1 + (size_t)base * 2);
        float4 wa = w1p[0], wb = w1p[1], wc = w1p[2], wd = w1p[3];
        float4 ba = *(const float4*)(b1 + base);
        float4 bb = *(const float4*)(b1 + base + 4);
        float h[8];
        h[0] = fmaxf(fmaf(t1, wa.y, fmaf(t0, wa.x, ba.x)), 0.f);
        h[1] = fmaxf(fmaf(t1, wa.w, fmaf(t0, wa.z, ba.y)), 0.f);
        h[2] = fmaxf(fmaf(t1, wb.y, fmaf(t0, wb.x, ba.z)), 0.f);
        h[3] = fmaxf(fmaf(t1, wb.w, fmaf(t0, wb.z, ba.w)), 0.f);
        h[4] = fmaxf(fmaf(t1, wc.y, fmaf(t0, wc.x, bb.x)), 0.f);
        h[5] = fmaxf(fmaf(t1, wc.w, fmaf(t0, wc.z, bb.y)), 0.f);
        h[6] = fmaxf(fmaf(t1, wd.y, fmaf(t0, wd.x, bb.z)), 0.f);
        h[7] = fmaxf(fmaf(t1, wd.w, fmaf(t0, wd.z, bb.w)), 0.f);

#pragma unroll
        for (int hh = 0; hh < 8; ++hh) {
            const float4* w2p = (const float4*)(w2 + (size_t)hh * 512 + base);
            float4 p0 = w2p[0], p1 = w2p[1];
            float s = h[0]*p0.x + h[1]*p0.y + h[2]*p0.z + h[3]*p0.w
                    + h[4]*p1.x + h[5]*p1.y + h[6]*p1.z + h[7]*p1.w;
#pragma unroll
            for (int off = 1; off <= 32; off <<= 1) s += __shfl_xor(s, off);
            if (lane == 0) cpbT[(size_t)hh * T + row] = f2h(s + b2[hh]);
        }
        return;
    }

    int idx = blockIdx.x * 256 + threadIdx.x;
    if (idx < n4) {
        float4 v = x[idx];
        ushort4 h;
        h.x = f2h(v.x); h.y = f2h(v.y); h.z = f2h(v.z); h.w = f2h(v.w);
        xh[idx] = h;
    }
    if (idx < 262144) {
        int nn = idx >> 8, k = idx & 255;
        float a;
        if (nn < 256)      a = qw[nn * 256 + k];
        else if (nn < 768) a = kvw[(nn - 256) * 256 + k];
        else               a = srw[(nn - 768) * 256 + k];
        Wall[idx] = f2h(a);
        rpi16[idx] = (ushort_t)rpi[idx];
    }
    if (idx < 65536) Pw[idx] = f2h(pw[idx]);
    if (idx < 1024) {
        float bv;
        if (idx < 256)      bv = qb[idx];
        else if (idx < 768) bv = kvb[idx - 256];
        else                bv = srb[idx - 768];
        ball[idx] = bv;
    }
}

// 8x8 average pool of x_sr fp16 (B,N,C) + LayerNorm -> xpool fp16 (B,64,C)
__global__ __launch_bounds__(256) void pool_ln(
    const ushort_t* __restrict__ xsr, const float* __restrict__ g,
    const float* __restrict__ be, ushort_t* __restrict__ xpool, int Hh, int Ww)
{
    const int C = 256;
    const int Nn = Hh * Ww;
    int b = blockIdx.x >> 6;
    int pidx = blockIdx.x & 63;
    int ph = pidx >> 3, pw = pidx & 7;
    int tid = threadIdx.x;
    float s = 0.f;
    for (int si = 0; si < 8; ++si) {
        int i = ph * 8 + si;
        const ushort_t* rowp = xsr + ((size_t)b * Nn + (size_t)i * Ww + pw * 8) * C + tid;
#pragma unroll
        for (int sj = 0; sj < 8; ++sj)
            s += (float)(*(const _Float16*)&rowp[(size_t)sj * C]);
    }
    s *= (1.f / 64.f);
    __shared__ float red[256];
    red[tid] = s; __syncthreads();
    for (int st = 128; st; st >>= 1) { if (tid < st) red[tid] += red[tid + st]; __syncthreads(); }
    float mean = red[0] * (1.f / 256.f);
    __syncthreads();
    float dv = s - mean;
    red[tid] = dv * dv; __syncthreads();
    for (int st = 128; st; st >>= 1) { if (tid < st) red[tid] += red[tid + st]; __syncthreads(); }
    float var = red[0] * (1.f / 256.f);
    xpool[(size_t)blockIdx.x * C + tid] = f2h(dv * rsqrtf(var + 1e-5f) * g[tid] + be[tid]);
}

// ---------------------------------------------------------------------------
// attn_v11: pool scores via MFMA; softmax in C-layout; quad AV from exp'd P;
// bias gather via ushort rpi + per-head fp16 cpbT (L1-resident).
// ---------------------------------------------------------------------------
__global__ __launch_bounds__(256) void attn_v11(
    const ushort_t* __restrict__ qh_g, // (8,M,32) fp16 raw q
    const ushort_t* __restrict__ kvh,  // (8,M,64) fp16 {k normed | v}
    const ushort_t* __restrict__ kvph, // (8,256,64) fp16 {k_pool normed | v_pool}
    const ushort_t* __restrict__ rpi16,// (N*64) table index (ushort)
    const ushort_t* __restrict__ cpbT, // (8,T) fp16 cpb, per-head
    const float* __restrict__ sls, const float* __restrict__ temp,
    const float* __restrict__ qe, const float* __restrict__ rbl,
    const float* __restrict__ ltok, const float* __restrict__ lbias,
    ushort_t* __restrict__ attno,      // (8,M,32) fp16
    int Mtot, int T)
{
    const int h = blockIdx.y, b = blockIdx.z;
    const int t = threadIdx.x;
    const int i = blockIdx.x;
    const int w = t >> 6;
    const int lane = t & 63;

    // token record = 64 halves = 8 x 16B chunks; phys chunk = logical^ (tok&7)
    __shared__ ushort_t kvloc[3 * 64 * 64];  // rows i-1..i+1 (clamped)
    __shared__ ushort_t kvp[64 * 64];        // pool k|v
    __shared__ ushort_t pb_s[64][66];        // pool bias [query][pool]
    __shared__ ushort_t Ps[64][72];          // exp'd pool probs (fp16), pad 72
    __shared__ float mzp[64][2];             // per-query pool {max, sum}
    __shared__ float lts[9][32];
    __shared__ float rbl_s[9], lb_s[9], qe_s[32];

    // ---- async coalesced stages ----
    {
        const int lt8 = lane >> 3, ls = lane & 7;
#pragma unroll
        for (int it = 0; it < 6; ++it) {
            const int u = it * 4 + w;            // 0..23
            const int dr = u >> 3, kB = u & 7;
            const int srcRow = min(max(i - 1 + dr, 0), 63);
            const int tok = kB * 8 + lt8;
            GLOAD16(kvh + ((size_t)h * Mtot + b * 4096 + srcRow * 64) * 64
                        + (size_t)(tok * 8 + (ls ^ (tok & 7))) * 8,
                    &kvloc[(size_t)(dr * 64 + kB * 8) * 64]);
        }
#pragma unroll
        for (int it = 0; it < 2; ++it) {
            const int u = it * 4 + w;            // 0..7
            const int tok = u * 8 + lt8;
            GLOAD16(kvph + ((size_t)h * 256 + b * 64) * 64
                         + (size_t)(tok * 8 + (ls ^ (tok & 7))) * 8,
                    &kvp[(size_t)(u * 8) * 64]);
        }
    }
    // ---- pb gather + tables (overlaps async stage latency) ----
    {
        const ushort_t* rp16 = rpi16 + (size_t)i * 4096;
        const ushort_t* ctab = cpbT + (size_t)h * T;
        for (int u = t; u < 4096; u += 256)
            pb_s[u >> 6][u & 63] = ctab[rp16[u]];
        for (int u = t; u < 288; u += 256) lts[u % 9][u / 9] = ltok[h * 288 + u];
        if (t < 9)  { rbl_s[t] = rbl[h * 9 + t]; lb_s[t] = lbias[h * 9 + t]; }
        if (t >= 64 && t < 96) qe_s[t - 64] = qe[h * 32 + (t - 64)];
    }
    __syncthreads();

    const int qi = lane >> 2;
    const int g4 = lane & 3;
    const int co = g4 * 8;
    const int j = w * 16 + qi;
    const int n = i * 64 + j;
    const size_t gq = (size_t)b * 4096 + n;

    const float tm = temp[h];
    const float sp = (tm > 20.f) ? tm : log1pf(expf(tm));

    // ---- load q slice (head-major), L2-normalize (quad DPP reduce) ----
    float qv[8];
    {
        const half8 q8 = *(const half8*)(qh_g + ((size_t)h * Mtot + gq) * 32 + co);
        float ss = 0.f;
#pragma unroll
        for (int d = 0; d < 8; ++d) { qv[d] = (float)q8[d]; ss += qv[d] * qv[d]; }
        ss = quad_sumf(ss);
        const float invn = 1.0f / fmaxf(sqrtf(ss), 1e-12f);
#pragma unroll
        for (int d = 0; d < 8; ++d) qv[d] *= invn;
    }

    // ---- learnable-token dots (fp32) ----
    float lt[9];
#pragma unroll
    for (int l = 0; l < 9; ++l) {
        float dl = 0.f;
        const float4* lw = (const float4*)&lts[l][co];
#pragma unroll
        for (int c4 = 0; c4 < 2; ++c4) {
            float4 w4 = lw[c4];
            dl += qv[4*c4+0]*w4.x + qv[4*c4+1]*w4.y + qv[4*c4+2]*w4.z + qv[4*c4+3]*w4.w;
        }
        dl = quad_sumf(dl);
        lt[l] = dl + lb_s[l];
    }

    // ---- scaled q -> fp16 pairs (quad layout) ----
    const float scal = sp * sls[n];
    half2_t qhp[4];
#pragma unroll
    for (int c = 0; c < 4; ++c) {
        float a = (qv[2*c+0] + qe_s[co + 2*c+0]) * scal;
        float bq = (qv[2*c+1] + qe_s[co + 2*c+1]) * scal;
        qhp[c] = half2_t{(_Float16)a, (_Float16)bq};
    }

    // ---- local scores (k from LDS, quad layout) ----
    float sl[9];
#pragma unroll
    for (int l = 0; l < 9; ++l) {
        const int di = l / 3 - 1, dj = l % 3 - 1;
        const int ii = i + di;
        const int jn = j + dj;
        const bool ok = (ii >= 0) && (ii < 64) && (jn >= 0) && (jn < 64);
        const int dr = di + 1;
        const int tokc = max(min(jn, 63), 0);
        const half8 k8 = *(const half8*)
            &kvloc[(size_t)((dr * 64 + tokc) * 8 + (g4 ^ (tokc & 7))) * 8];
        float dk = 0.f;
        dk = fdot2f(qhp[0], __builtin_shufflevector(k8, k8, 0, 1), dk);
        dk = fdot2f(qhp[1], __builtin_shufflevector(k8, k8, 2, 3), dk);
        dk = fdot2f(qhp[2], __builtin_shufflevector(k8, k8, 4, 5), dk);
        dk = fdot2f(qhp[3], __builtin_shufflevector(k8, k8, 6, 7), dk);
        dk = quad_sumf(dk);
        sl[l] = ok ? (dk + rbl_s[l]) : -INFINITY;
    }
    float m_l = sl[0];
#pragma unroll
    for (int l = 1; l < 9; ++l) m_l = fmaxf(m_l, sl[l]);

    // ---- pool scores via MFMA -------------------------------------------
    const int fr = lane & 15;
    const int cn = lane >> 4;           // k-chunk / reg-group
    const int q4 = cn * 4;
    half8 af;
    {
        const int sidx = (4 * fr + cn) << 2;
        int4_t ai;
        ai.x = __builtin_amdgcn_ds_bpermute(sidx, __builtin_bit_cast(int, qhp[0]));
        ai.y = __builtin_amdgcn_ds_bpermute(sidx, __builtin_bit_cast(int, qhp[1]));
        ai.z = __builtin_amdgcn_ds_bpermute(sidx, __builtin_bit_cast(int, qhp[2]));
        ai.w = __builtin_amdgcn_ds_bpermute(sidx, __builtin_bit_cast(int, qhp[3]));
        af = __builtin_bit_cast(half8, ai);
    }
    f32x4 acc[4];
#pragma unroll
    for (int ct = 0; ct < 4; ++ct) {
#pragma unroll
        for (int r = 0; r < 4; ++r)
            acc[ct][r] = (float)(*(const _Float16*)&pb_s[w * 16 + q4 + r][ct * 16 + fr]);
    }
#pragma unroll
    for (int ct = 0; ct < 4; ++ct) {
        const int tok = ct * 16 + fr;
        const half8 bf = *(const half8*)&kvp[(size_t)(tok * 8 + (cn ^ (tok & 7))) * 8];
        acc[ct] = __builtin_amdgcn_mfma_f32_16x16x32_f16(af, bf, acc[ct], 0, 0, 0);
    }

    // ---- pool softmax in C-layout (rows q4+r, cols ct*16+fr) ----
#pragma unroll
    for (int r = 0; r < 4; ++r) {
        float mm = fmaxf(fmaxf(acc[0][r], acc[1][r]), fmaxf(acc[2][r], acc[3][r]));
        mm = max16f(mm);
        float z = 0.f;
        float pv[4];
#pragma unroll
        for (int ct = 0; ct < 4; ++ct) {
            pv[ct] = __expf(acc[ct][r] - mm);
            z += pv[ct];
        }
        z = sum16f(z);
#pragma unroll
        for (int ct = 0; ct < 4; ++ct)
            Ps[w * 16 + q4 + r][ct * 16 + fr] = f2h(pv[ct]);
        if (fr == 0) { mzp[w * 16 + q4 + r][0] = mm; mzp[w * 16 + q4 + r][1] = z; }
    }
    // rows written/read by the same wave -> lgkmcnt ordering suffices

    // ---- merge + AV (quad layout) ----
    const float m_p = mzp[j][0];
    const float Z_p = mzp[j][1];
    const float m = fmaxf(m_l, m_p);
    const float fp = __expf(m_p - m);
    float Z = Z_p * fp;
    const _Float16 fh = (_Float16)fp;

    half2_t oh[4];
#pragma unroll
    for (int c = 0; c < 4; ++c) oh[c] = half2_t{(_Float16)0.f, (_Float16)0.f};

#pragma unroll
    for (int cch = 0; cch < 8; ++cch) {
        const half8 p8 = *(const half8*)&Ps[j][cch * 8];
#pragma unroll
        for (int k = 0; k < 8; ++k) {
            const int p = cch * 8 + k;
            const _Float16 ah = p8[k] * fh;
            const half2_t a2 = half2_t{ah, ah};
            const half8 v8 = *(const half8*)
                &kvp[(size_t)(p * 8 + ((4 + g4) ^ (p & 7))) * 8];
            oh[0] = a2 * __builtin_shufflevector(v8, v8, 0, 1) + oh[0];
            oh[1] = a2 * __builtin_shufflevector(v8, v8, 2, 3) + oh[1];
            oh[2] = a2 * __builtin_shufflevector(v8, v8, 4, 5) + oh[2];
            oh[3] = a2 * __builtin_shufflevector(v8, v8, 6, 7) + oh[3];
        }
    }

    // ---- local exps with final m ----
#pragma unroll
    for (int l = 0; l < 9; ++l) { sl[l] = __expf(sl[l] - m); Z += sl[l]; }

    // ---- local AV from LDS: coef = el + lt*Z (final *invZ) ----
#pragma unroll
    for (int l = 0; l < 9; ++l) {
        const int di = l / 3 - 1, dj = l % 3 - 1;
        const int ii = i + di;
        const int jn = j + dj;
        const bool ok = (ii >= 0) && (ii < 64) && (jn >= 0) && (jn < 64);
        const int dr = di + 1;
        const int tokc = max(min(jn, 63), 0);
        const float coef = ok ? (sl[l] + lt[l] * Z) : 0.f;
        const half8 v8 = *(const half8*)
            &kvloc[(size_t)((dr * 64 + tokc) * 8 + ((4 + g4) ^ (tokc & 7))) * 8];
        const _Float16 ch = (_Float16)coef;
        const half2_t c2 = half2_t{ch, ch};
        oh[0] = c2 * __builtin_shufflevector(v8, v8, 0, 1) + oh[0];
        oh[1] = c2 * __builtin_shufflevector(v8, v8, 2, 3) + oh[1];
        oh[2] = c2 * __builtin_shufflevector(v8, v8, 4, 5) + oh[2];
        oh[3] = c2 * __builtin_shufflevector(v8, v8, 6, 7) + oh[3];
    }

    // ---- normalize and store fp16 (head-major, coalesced) ----
    const float invZ = 1.0f / Z;
    ushort4* outp = (ushort4*)(attno + ((size_t)h * Mtot + gq) * 32 + co);
#pragma unroll
    for (int c4 = 0; c4 < 2; ++c4) {
        ushort4 u;
        u.x = f2h((float)oh[2*c4+0][0] * invZ);
        u.y = f2h((float)oh[2*c4+0][1] * invZ);
        u.z = f2h((float)oh[2*c4+1][0] * invZ);
        u.w = f2h((float)oh[2*c4+1][1] * invZ);
        outp[c4] = u;
    }
}

extern "C" void kernel_launch(void* const* d_in, const int* in_sizes, int n_in,
                              void* d_out, int out_size, void* d_ws, size_t ws_size,
                              hipStream_t stream)
{
    const float* x    = (const float*)d_in[0];
    const float* tbl  = (const float*)d_in[1];
    const float* sls  = (const float*)d_in[2];
    const float* q_w  = (const float*)d_in[3];
    const float* q_b  = (const float*)d_in[4];
    const float* kv_w = (const float*)d_in[5];
    const float* kv_b = (const float*)d_in[6];
    const float* temp = (const float*)d_in[7];
    const float* qe   = (const float*)d_in[8];
    const float* sr_w = (const float*)d_in[9];
    const float* sr_b = (const float*)d_in[10];
    const float* ng   = (const float*)d_in[11];
    const float* nb   = (const float*)d_in[12];
    const float* f1w  = (const float*)d_in[13];
    const float* f1b  = (const float*)d_in[14];
    const float* f2w  = (const float*)d_in[15];
    const float* f2b  = (const float*)d_in[16];
    const float* rbl  = (const float*)d_in[17];
    const float* ltok = (const float*)d_in[18];
    const float* lbias= (const float*)d_in[19];
    const float* pw   = (const float*)d_in[20];
    const float* pb   = (const float*)d_in[21];
    const int*   rpi  = (const int*)d_in[22];

    const int C = 256, Hh = 64, Ww = 64, Nn = Hh * Ww;
    const int B = in_sizes[0] / (Nn * C);   // 4
    const int T = in_sizes[1] / 2;
    const int M = B * Nn;                   // 16384

    float* ws = (float*)d_ws;
    size_t o = 0;
    ushort_t* qh    = (ushort_t*)(ws + o); o += (size_t)M * C / 2;     // fp16 (8,M,32)
    ushort_t* kvh   = (ushort_t*)(ws + o); o += (size_t)M * C;         // fp16 (8,M,64)
    ushort_t* xsrh  = (ushort_t*)(ws + o); o += (size_t)M * C / 2;     // fp16 xsr (M,256)
    ushort_t* xpoolh= (ushort_t*)(ws + o); o += (size_t)B * 64 * C / 2;// fp16 x_pool
    ushort_t* kvph  = (ushort_t*)(ws + o); o += (size_t)B * 64 * C;    // fp16 (8,256,64)
    ushort_t* cpbT  = (ushort_t*)(ws + o); o += (size_t)T * 4 + 4;     // fp16 (8,T)
    ushort_t* rpi16 = (ushort_t*)(ws + o); o += 131072;                // ushort (N*64)
    ushort_t* xh   = (ushort_t*)(ws + o); o += (size_t)M * C / 2;      // fp16 x; reused as attno
    ushort_t* Wall = (ushort_t*)(ws + o); o += 1024 * 256 / 2;
    ushort_t* Pwh  = (ushort_t*)(ws + o); o += 256 * 256 / 2;
    float* ball = ws + o; o += 1024;
    ushort_t* attno_hf = xh;   // xh dead after the x-GEMM; (8,M,32)

    dim3 blk(256);
    const int n4x = M * C / 4;
    const int nprep = (n4x + 255) / 256;    // 4096
    const int ncpb  = (T + 3) / 4;

    // prep (cast x + pack weights + rpi16) + cpb MLP (fp16 transposed)
    prep_cpb<<<nprep + ncpb, blk, 0, stream>>>(
        (const float4*)x, (ushort4*)xh, n4x,
        nprep, q_w, kv_w, sr_w, pw, q_b, kv_b, sr_b, rpi, rpi16,
        Wall, Pwh, ball, tbl, f1w, f1b, f2w, f2b, cpbT, T);
    // fused [q | k(norm) | v | sr(gelu)] fp16 GEMM, 128x128 tile
    mfma_hgemm<128, 128, false><<<dim3(8, M / 128), blk, 0, stream>>>(
        xh, Wall, ball, nullptr, qh, kvh, xsrh, 0, M);
    // pool + LN (fp16 out)
    pool_ln<<<B * 64, blk, 0, stream>>>(xsrh, ng, nb, xpoolh, Hh, Ww);
    // kv_p fp16 MFMA GEMM with fused k_pool head-norm (head-major out)
    mfma_hgemm<64, 64, false><<<dim3(8, (B * 64) / 64), blk, 0, stream>>>(
        xpoolh, Wall + 256 * 256, ball + 256, nullptr, nullptr, kvph, nullptr, 2, B * 64);
    // attention (head-major in/out; MFMA pool scores; L1-resident bias gather)
    attn_v11<<<dim3(64, 8, B), blk, 0, stream>>>(
        qh, kvh, kvph, rpi16, cpbT, sls, temp, qe, rbl, ltok, lbias, attno_hf, M, T);
    // proj fp16 GEMM, 128x128 tile; A = attno head-major
    mfma_hgemm<128, 128, true><<<dim3(2, M / 128), blk, 0, stream>>>(
        attno_hf, Pwh, pb, (float*)d_out, nullptr, nullptr, nullptr, 1, M);
}

// Round 7
// 212.026 us; speedup vs baseline: 1.0794x; 1.0794x over previous
//
#include <hip/hip_runtime.h>
#include <math.h>

// ---------------------------------------------------------------------------
// TransNeXt aggregated attention. Round 18:
//  - Tiles REVERTED to the proven fast config: x-GEMM <128,64> (2048 blocks),
//    proj/kv_p <64,64>. R2/R3/R6 triangulate: 128x128 is stall-bound at
//    ~45.5us regardless of pipeline style; 128x64's extra block-parallelism
//    is the lever (R6 post-mortem).
//  - Depth-3 LDS pipeline (36KB at <128,64>, 4 blocks/CU): two stages in
//    flight, steady-state s_waitcnt vmcnt(2*LPS), hand-peeled 8-stage loop
//    with exact tail counts.
//  - Keeps R6's attn wins: rpi16 + per-head fp16 cpbT gather, MFMA pool
//    scores, head-major layouts.
//  6 dispatches.
// B=4, H=W=64, C=256, NH=8, hd=32, LOCAL_LEN=9, pool 8x8=64
// ---------------------------------------------------------------------------

typedef unsigned short ushort_t;
typedef __attribute__((ext_vector_type(8))) _Float16 half8;
typedef __attribute__((ext_vector_type(2))) _Float16 half2_t;
typedef __attribute__((ext_vector_type(4))) float f32x4;
typedef __attribute__((ext_vector_type(4))) int int4_t;

static __device__ __forceinline__ ushort_t f2h(float f) {
    _Float16 h = (_Float16)f;           // RTNE
    return *(ushort_t*)&h;
}

static __device__ __forceinline__ float fdot2f(half2_t a, half2_t b, float c) {
#if __has_builtin(__builtin_amdgcn_fdot2)
    return __builtin_amdgcn_fdot2(a, b, c, false);
#else
    return (float)a[0] * (float)b[0] + (float)a[1] * (float)b[1] + c;
#endif
}

// ---- DPP lane reductions (VALU pipe) --------------------------------------
template <int CTRL>
static __device__ __forceinline__ float dpp_addf(float x) {
    int v = __builtin_amdgcn_update_dpp(
        0, __builtin_bit_cast(int, x), CTRL, 0xF, 0xF, true);
    return x + __builtin_bit_cast(float, v);
}
template <int CTRL>
static __device__ __forceinline__ float dpp_maxf(float x) {
    int v = __builtin_amdgcn_update_dpp(
        0, __builtin_bit_cast(int, x), CTRL, 0xF, 0xF, true);
    return fmaxf(x, __builtin_bit_cast(float, v));
}
static __device__ __forceinline__ float quad_sumf(float x) {
    return dpp_addf<0x4E>(dpp_addf<0xB1>(x));
}
static __device__ __forceinline__ float sum16f(float x) {
    return dpp_addf<0x128>(dpp_addf<0x124>(quad_sumf(x)));
}
static __device__ __forceinline__ float max16f(float x) {
    return dpp_maxf<0x128>(dpp_maxf<0x124>(dpp_maxf<0x4E>(dpp_maxf<0xB1>(x))));
}

#define GLOAD16(g, l)                                                        \
    __builtin_amdgcn_global_load_lds(                                        \
        (const __attribute__((address_space(1))) unsigned int*)(g),          \
        (__attribute__((address_space(3))) unsigned int*)(l), 16, 0, 0)

// ---------------------------------------------------------------------------
// mfma_hgemm<TM,TN,AHM>: C = A @ W^T + bias, fp16 in, fp32 accum.
// 4 waves 2x2; depth-3 counted-vmcnt pipeline; LDS XOR-swizzle.
// AHM: A is head-major (8, Arows, 32) -- one head per BK=32 K-step.
// mode 0: qh (8,M,32) | kvh k normed (8,M,64) | kvh v | gelu -> xsrh (M,256)
// mode 1 (proj, N=256): out0 fp32 (M,256)
// mode 2 (kv_p, N=512): kvph (8,Arows,64), k normed
// ---------------------------------------------------------------------------
template <int TM, int TN, bool AHM>
__global__ __launch_bounds__(256) void mfma_hgemm(
    const ushort_t* __restrict__ Ag, const ushort_t* __restrict__ Bg,
    const float* __restrict__ bias, float* __restrict__ out0,
    ushort_t* __restrict__ qh_out, ushort_t* __restrict__ kvh,
    ushort_t* __restrict__ xsrh, int mode, int Arows)
{
    const int K = 256;                      // 8 stages of BK=32
    const int IM = TM / 32;
    const int JN = TN / 32;
    constexpr int LPS = TM / 64 + TN / 64;  // global_load_lds per thread/stage
    __shared__ ushort_t Ah[3][TM * 32];
    __shared__ ushort_t Bh[3][TN * 32];

    const int t = threadIdx.x;
    const int w = t >> 6;
    const int lane = t & 63;

    // XCD-aware bijective chunk swizzle (all grids are %8 == 0)
    const int nwg = gridDim.x * gridDim.y;
    int wg = blockIdx.y * gridDim.x + blockIdx.x;
    wg = (wg & 7) * (nwg >> 3) + (wg >> 3);
    const int bm = (wg / gridDim.x) * TM;
    const int bn = (wg % gridDim.x) * TN;

    const int wm = (w >> 1) * (TM / 2);
    const int wn = (w & 1) * (TN / 2);

    f32x4 acc[IM][JN];
#pragma unroll
    for (int i = 0; i < IM; ++i)
#pragma unroll
        for (int j = 0; j < JN; ++j) acc[i][j] = f32x4{0.f, 0.f, 0.f, 0.f};

    const int lrow  = t >> 2;
    const int lk8sw = ((t & 3) ^ ((t >> 3) & 3)) * 8;  // pre-swizzled src col

#define STAGE(bufi, k0s)                                                     \
    do {                                                                     \
        _Pragma("unroll")                                                    \
        for (int r = 0; r < TM / 64; ++r) {                                  \
            const ushort_t* srcA = AHM                                       \
                ? Ag + ((size_t)((k0s) >> 5) * Arows + (bm + r * 64 + lrow)) * 32 + lk8sw \
                : Ag + (size_t)(bm + r * 64 + lrow) * K + (k0s) + lk8sw;     \
            GLOAD16(srcA, &Ah[bufi][(unsigned)(r * 64 + w * 16) * 32]);      \
        }                                                                    \
        _Pragma("unroll")                                                    \
        for (int r = 0; r < TN / 64; ++r)                                    \
            GLOAD16(Bg + (size_t)(bn + r * 64 + lrow) * K + (k0s) + lk8sw,   \
                    &Bh[bufi][(unsigned)(r * 64 + w * 16) * 32]);            \
    } while (0)

    const int fr   = lane & 15;
    const int sws8 = ((lane >> 4) ^ ((fr >> 1) & 3)) * 8;  // swizzled read slot

#define COMPUTE(bufi)                                                        \
    do {                                                                     \
        half8 af[IM], bf[JN];                                                \
        _Pragma("unroll")                                                    \
        for (int i2 = 0; i2 < IM; ++i2)                                      \
            af[i2] = *(const half8*)&Ah[bufi][(unsigned)(wm + i2 * 16 + fr) * 32 + sws8]; \
        _Pragma("unroll")                                                    \
        for (int j2 = 0; j2 < JN; ++j2)                                      \
            bf[j2] = *(const half8*)&Bh[bufi][(unsigned)(wn + j2 * 16 + fr) * 32 + sws8]; \
        __builtin_amdgcn_s_setprio(1);                                       \
        _Pragma("unroll")                                                    \
        for (int i2 = 0; i2 < IM; ++i2)                                      \
            _Pragma("unroll")                                                \
            for (int j2 = 0; j2 < JN; ++j2)                                  \
                acc[i2][j2] = __builtin_amdgcn_mfma_f32_16x16x32_f16(        \
                    af[i2], bf[j2], acc[i2][j2], 0, 0, 0);                   \
        __builtin_amdgcn_s_setprio(0);                                       \
    } while (0)

// One pipeline iteration: wait until stage S's loads landed (counted),
// barrier, compute, barrier, then re-stage buffer S%3 for stage S+3.
#define PIPE_ITER(S, NCNT, DOSTAGE)                                          \
    do {                                                                     \
        asm volatile("s_waitcnt vmcnt(%0)" :: "n"(NCNT) : "memory");         \
        __builtin_amdgcn_s_barrier();                                        \
        asm volatile("" ::: "memory");                                       \
        COMPUTE((S) % 3);                                                    \
        asm volatile("" ::: "memory");                                       \
        __builtin_amdgcn_s_barrier();                                        \
        asm volatile("" ::: "memory");                                       \
        if (DOSTAGE) STAGE((S) % 3, ((S) + 3) * 32);                         \
    } while (0)

    STAGE(0, 0);
    STAGE(1, 32);
    STAGE(2, 64);
    PIPE_ITER(0, 2 * LPS, true);
    PIPE_ITER(1, 2 * LPS, true);
    PIPE_ITER(2, 2 * LPS, true);
    PIPE_ITER(3, 2 * LPS, true);
    PIPE_ITER(4, 2 * LPS, true);
    PIPE_ITER(5, 2 * LPS, false);
    PIPE_ITER(6, 1 * LPS, false);
    PIPE_ITER(7, 0, false);
#undef PIPE_ITER
#undef COMPUTE
#undef STAGE

    // epilogue: C/D layout col=lane&15, row=(lane>>4)*4+reg.
    const int q4 = (lane >> 4) * 4;
#pragma unroll
    for (int i = 0; i < IM; ++i) {
#pragma unroll
        for (int jp = 0; jp < JN / 2; ++jp) {
#pragma unroll
            for (int r = 0; r < 4; ++r) {
                const int row = bm + wm + i * 16 + q4 + r;
                const int col0 = bn + wn + jp * 32 + fr;
                const int col1 = col0 + 16;
                float v0 = acc[i][2 * jp][r] + bias[col0];
                float v1 = acc[i][2 * jp + 1][r] + bias[col1];
                if (mode == 0) {
                    if (col0 < 256) {
                        const size_t base = ((size_t)(col0 >> 5) * Arows + row) * 32;
                        qh_out[base + fr]      = f2h(v0);
                        qh_out[base + fr + 16] = f2h(v1);
                    } else if (col0 < 512) {   // k: fused per-head L2 norm
                        const float ss = sum16f(v0 * v0 + v1 * v1);
                        const float invn = 1.0f / fmaxf(sqrtf(ss), 1e-12f);
                        const size_t base = ((size_t)((col0 - 256) >> 5) * Arows + row) * 64;
                        kvh[base + fr]      = f2h(v0 * invn);
                        kvh[base + fr + 16] = f2h(v1 * invn);
                    } else if (col0 < 768) {   // v
                        const size_t base = ((size_t)((col0 - 512) >> 5) * Arows + row) * 64 + 32;
                        kvh[base + fr]      = f2h(v0);
                        kvh[base + fr + 16] = f2h(v1);
                    } else {                    // sr + gelu (row-major kept)
                        v0 = 0.5f * v0 * (1.0f + erff(v0 * 0.70710678118654752f));
                        v1 = 0.5f * v1 * (1.0f + erff(v1 * 0.70710678118654752f));
                        xsrh[(size_t)row * 256 + (col0 - 768)] = f2h(v0);
                        xsrh[(size_t)row * 256 + (col1 - 768)] = f2h(v1);
                    }
                } else if (mode == 2) {         // kv_p head-major
                    if (col0 < 256) {           // k_pool: fused per-head norm
                        const float ss = sum16f(v0 * v0 + v1 * v1);
                        const float invn = 1.0f / fmaxf(sqrtf(ss), 1e-12f);
                        const size_t base = ((size_t)(col0 >> 5) * Arows + row) * 64;
                        kvh[base + fr]      = f2h(v0 * invn);
                        kvh[base + fr + 16] = f2h(v1 * invn);
                    } else {
                        const size_t base = ((size_t)((col0 - 256) >> 5) * Arows + row) * 64 + 32;
                        kvh[base + fr]      = f2h(v0);
                        kvh[base + fr + 16] = f2h(v1);
                    }
                } else {
                    out0[(size_t)row * 256 + col0] = v0;
                    out0[(size_t)row * 256 + col1] = v1;
                }
            }
        }
    }
}

// prep_cpb: x cast + weight/bias packing + rpi->ushort + cpb MLP (fp16,
// transposed per-head) in one kernel.
__global__ __launch_bounds__(256) void prep_cpb(
    const float4* __restrict__ x, ushort4* __restrict__ xh, int n4, int nprep,
    const float* __restrict__ qw, const float* __restrict__ kvw,
    const float* __restrict__ srw, const float* __restrict__ pw,
    const float* __restrict__ qb, const float* __restrict__ kvb,
    const float* __restrict__ srb,
    const int* __restrict__ rpi, ushort_t* __restrict__ rpi16,
    ushort_t* __restrict__ Wall, ushort_t* __restrict__ Pw,
    float* __restrict__ ball,
    const float* __restrict__ table, const float* __restrict__ w1,
    const float* __restrict__ b1, const float* __restrict__ w2,
    const float* __restrict__ b2, ushort_t* __restrict__ cpbT, int T)
{
    if (blockIdx.x >= nprep) {
        const int wv = threadIdx.x >> 6;
        const int lane = threadIdx.x & 63;
        const int row = (blockIdx.x - nprep) * 4 + wv;
        if (row >= T) return;
        const float t0 = table[(size_t)row * 2];
        const float t1 = table[(size_t)row * 2 + 1];
        const int base = lane * 8;

        const float4* w1p = (const float4*)(w1 + (size_t)base * 2);
        float4 wa = w1p[0], wb = w1p[1], wc = w1p[2], wd = w1p[3];
        float4 ba = *(const float4*)(b1 + base);
        float4 bb = *(const float4*)(b1 + base + 4);
        float h[8];
        h[0] = fmaxf(fmaf(t1, wa.y, fmaf(t0, wa.x, ba.x)), 0.f);
        h[1] = fmaxf(fmaf(t1, wa.w, fmaf(t0, wa.z, ba.y)), 0.f);
        h[2] = fmaxf(fmaf(t1, wb.y, fmaf(t0, wb.x, ba.z)), 0.f);
        h[3] = fmaxf(fmaf(t1, wb.w, fmaf(t0, wb.z, ba.w)), 0.f);
        h[4] = fmaxf(fmaf(t1, wc.y, fmaf(t0, wc.x, bb.x)), 0.f);
        h[5] = fmaxf(fmaf(t1, wc.w, fmaf(t0, wc.z, bb.y)), 0.f);
        h[6] = fmaxf(fmaf(t1, wd.y, fmaf(t0, wd.x, bb.z)), 0.f);
        h[7] = fmaxf(fmaf(t1, wd.w, fmaf(t0, wd.z, bb.w)), 0.f);

#pragma unroll
        for (int hh = 0; hh < 8; ++hh) {
            const float4* w2p = (const float4*)(w2 + (size_t)hh * 512 + base);
            float4 p0 = w2p[0], p1 = w2p[1];
            float s = h[0]*p0.x + h[1]*p0.y + h[2]*p0.z + h[3]*p0.w
                    + h[4]*p1.x + h[5]*p1.y + h[6]*p1.z + h[7]*p1.w;
#pragma unroll
            for (int off = 1; off <= 32; off <<= 1) s += __shfl_xor(s, off);
            if (lane == 0) cpbT[(size_t)hh * T + row] = f2h(s + b2[hh]);
        }
        return;
    }

    int idx = blockIdx.x * 256 + threadIdx.x;
    if (idx < n4) {
        float4 v = x[idx];
        ushort4 h;
        h.x = f2h(v.x); h.y = f2h(v.y); h.z = f2h(v.z); h.w = f2h(v.w);
        xh[idx] = h;
    }
    if (idx < 262144) {
        int nn = idx >> 8, k = idx & 255;
        float a;
        if (nn < 256)      a = qw[nn * 256 + k];
        else if (nn < 768) a = kvw[(nn - 256) * 256 + k];
        else               a = srw[(nn - 768) * 256 + k];
        Wall[idx] = f2h(a);
        rpi16[idx] = (ushort_t)rpi[idx];
    }
    if (idx < 65536) Pw[idx] = f2h(pw[idx]);
    if (idx < 1024) {
        float bv;
        if (idx < 256)      bv = qb[idx];
        else if (idx < 768) bv = kvb[idx - 256];
        else                bv = srb[idx - 768];
        ball[idx] = bv;
    }
}

// 8x8 average pool of x_sr fp16 (B,N,C) + LayerNorm -> xpool fp16 (B,64,C)
__global__ __launch_bounds__(256) void pool_ln(
    const ushort_t* __restrict__ xsr, const float* __restrict__ g,
    const float* __restrict__ be, ushort_t* __restrict__ xpool, int Hh, int Ww)
{
    const int C = 256;
    const int Nn = Hh * Ww;
    int b = blockIdx.x >> 6;
    int pidx = blockIdx.x & 63;
    int ph = pidx >> 3, pw = pidx & 7;
    int tid = threadIdx.x;
    float s = 0.f;
    for (int si = 0; si < 8; ++si) {
        int i = ph * 8 + si;
        const ushort_t* rowp = xsr + ((size_t)b * Nn + (size_t)i * Ww + pw * 8) * C + tid;
#pragma unroll
        for (int sj = 0; sj < 8; ++sj)
            s += (float)(*(const _Float16*)&rowp[(size_t)sj * C]);
    }
    s *= (1.f / 64.f);
    __shared__ float red[256];
    red[tid] = s; __syncthreads();
    for (int st = 128; st; st >>= 1) { if (tid < st) red[tid] += red[tid + st]; __syncthreads(); }
    float mean = red[0] * (1.f / 256.f);
    __syncthreads();
    float dv = s - mean;
    red[tid] = dv * dv; __syncthreads();
    for (int st = 128; st; st >>= 1) { if (tid < st) red[tid] += red[tid + st]; __syncthreads(); }
    float var = red[0] * (1.f / 256.f);
    xpool[(size_t)blockIdx.x * C + tid] = f2h(dv * rsqrtf(var + 1e-5f) * g[tid] + be[tid]);
}

// ---------------------------------------------------------------------------
// attn_v11: pool scores via MFMA; softmax in C-layout; quad AV from exp'd P;
// bias gather via ushort rpi + per-head fp16 cpbT (L1-resident).
// ---------------------------------------------------------------------------
__global__ __launch_bounds__(256) void attn_v11(
    const ushort_t* __restrict__ qh_g, // (8,M,32) fp16 raw q
    const ushort_t* __restrict__ kvh,  // (8,M,64) fp16 {k normed | v}
    const ushort_t* __restrict__ kvph, // (8,256,64) fp16 {k_pool normed | v_pool}
    const ushort_t* __restrict__ rpi16,// (N*64) table index (ushort)
    const ushort_t* __restrict__ cpbT, // (8,T) fp16 cpb, per-head
    const float* __restrict__ sls, const float* __restrict__ temp,
    const float* __restrict__ qe, const float* __restrict__ rbl,
    const float* __restrict__ ltok, const float* __restrict__ lbias,
    ushort_t* __restrict__ attno,      // (8,M,32) fp16
    int Mtot, int T)
{
    const int h = blockIdx.y, b = blockIdx.z;
    const int t = threadIdx.x;
    const int i = blockIdx.x;
    const int w = t >> 6;
    const int lane = t & 63;

    // token record = 64 halves = 8 x 16B chunks; phys chunk = logical^ (tok&7)
    __shared__ ushort_t kvloc[3 * 64 * 64];  // rows i-1..i+1 (clamped)
    __shared__ ushort_t kvp[64 * 64];        // pool k|v
    __shared__ ushort_t pb_s[64][66];        // pool bias [query][pool]
    __shared__ ushort_t Ps[64][72];          // exp'd pool probs (fp16), pad 72
    __shared__ float mzp[64][2];             // per-query pool {max, sum}
    __shared__ float lts[9][32];
    __shared__ float rbl_s[9], lb_s[9], qe_s[32];

    // ---- async coalesced stages ----
    {
        const int lt8 = lane >> 3, ls = lane & 7;
#pragma unroll
        for (int it = 0; it < 6; ++it) {
            const int u = it * 4 + w;            // 0..23
            const int dr = u >> 3, kB = u & 7;
            const int srcRow = min(max(i - 1 + dr, 0), 63);
            const int tok = kB * 8 + lt8;
            GLOAD16(kvh + ((size_t)h * Mtot + b * 4096 + srcRow * 64) * 64
                        + (size_t)(tok * 8 + (ls ^ (tok & 7))) * 8,
                    &kvloc[(size_t)(dr * 64 + kB * 8) * 64]);
        }
#pragma unroll
        for (int it = 0; it < 2; ++it) {
            const int u = it * 4 + w;            // 0..7
            const int tok = u * 8 + lt8;
            GLOAD16(kvph + ((size_t)h * 256 + b * 64) * 64
                         + (size_t)(tok * 8 + (ls ^ (tok & 7))) * 8,
                    &kvp[(size_t)(u * 8) * 64]);
        }
    }
    // ---- pb gather + tables (overlaps async stage latency) ----
    {
        const ushort_t* rp16 = rpi16 + (size_t)i * 4096;
        const ushort_t* ctab = cpbT + (size_t)h * T;
        for (int u = t; u < 4096; u += 256)
            pb_s[u >> 6][u & 63] = ctab[rp16[u]];
        for (int u = t; u < 288; u += 256) lts[u % 9][u / 9] = ltok[h * 288 + u];
        if (t < 9)  { rbl_s[t] = rbl[h * 9 + t]; lb_s[t] = lbias[h * 9 + t]; }
        if (t >= 64 && t < 96) qe_s[t - 64] = qe[h * 32 + (t - 64)];
    }
    __syncthreads();

    const int qi = lane >> 2;
    const int g4 = lane & 3;
    const int co = g4 * 8;
    const int j = w * 16 + qi;
    const int n = i * 64 + j;
    const size_t gq = (size_t)b * 4096 + n;

    const float tm = temp[h];
    const float sp = (tm > 20.f) ? tm : log1pf(expf(tm));

    // ---- load q slice (head-major), L2-normalize (quad DPP reduce) ----
    float qv[8];
    {
        const half8 q8 = *(const half8*)(qh_g + ((size_t)h * Mtot + gq) * 32 + co);
        float ss = 0.f;
#pragma unroll
        for (int d = 0; d < 8; ++d) { qv[d] = (float)q8[d]; ss += qv[d] * qv[d]; }
        ss = quad_sumf(ss);
        const float invn = 1.0f / fmaxf(sqrtf(ss), 1e-12f);
#pragma unroll
        for (int d = 0; d < 8; ++d) qv[d] *= invn;
    }

    // ---- learnable-token dots (fp32) ----
    float lt[9];
#pragma unroll
    for (int l = 0; l < 9; ++l) {
        float dl = 0.f;
        const float4* lw = (const float4*)&lts[l][co];
#pragma unroll
        for (int c4 = 0; c4 < 2; ++c4) {
            float4 w4 = lw[c4];
            dl += qv[4*c4+0]*w4.x + qv[4*c4+1]*w4.y + qv[4*c4+2]*w4.z + qv[4*c4+3]*w4.w;
        }
        dl = quad_sumf(dl);
        lt[l] = dl + lb_s[l];
    }

    // ---- scaled q -> fp16 pairs (quad layout) ----
    const float scal = sp * sls[n];
    half2_t qhp[4];
#pragma unroll
    for (int c = 0; c < 4; ++c) {
        float a = (qv[2*c+0] + qe_s[co + 2*c+0]) * scal;
        float bq = (qv[2*c+1] + qe_s[co + 2*c+1]) * scal;
        qhp[c] = half2_t{(_Float16)a, (_Float16)bq};
    }

    // ---- local scores (k from LDS, quad layout) ----
    float sl[9];
#pragma unroll
    for (int l = 0; l < 9; ++l) {
        const int di = l / 3 - 1, dj = l % 3 - 1;
        const int ii = i + di;
        const int jn = j + dj;
        const bool ok = (ii >= 0) && (ii < 64) && (jn >= 0) && (jn < 64);
        const int dr = di + 1;
        const int tokc = max(min(jn, 63), 0);
        const half8 k8 = *(const half8*)
            &kvloc[(size_t)((dr * 64 + tokc) * 8 + (g4 ^ (tokc & 7))) * 8];
        float dk = 0.f;
        dk = fdot2f(qhp[0], __builtin_shufflevector(k8, k8, 0, 1), dk);
        dk = fdot2f(qhp[1], __builtin_shufflevector(k8, k8, 2, 3), dk);
        dk = fdot2f(qhp[2], __builtin_shufflevector(k8, k8, 4, 5), dk);
        dk = fdot2f(qhp[3], __builtin_shufflevector(k8, k8, 6, 7), dk);
        dk = quad_sumf(dk);
        sl[l] = ok ? (dk + rbl_s[l]) : -INFINITY;
    }
    float m_l = sl[0];
#pragma unroll
    for (int l = 1; l < 9; ++l) m_l = fmaxf(m_l, sl[l]);

    // ---- pool scores via MFMA -------------------------------------------
    const int fr = lane & 15;
    const int cn = lane >> 4;           // k-chunk / reg-group
    const int q4 = cn * 4;
    half8 af;
    {
        const int sidx = (4 * fr + cn) << 2;
        int4_t ai;
        ai.x = __builtin_amdgcn_ds_bpermute(sidx, __builtin_bit_cast(int, qhp[0]));
        ai.y = __builtin_amdgcn_ds_bpermute(sidx, __builtin_bit_cast(int, qhp[1]));
        ai.z = __builtin_amdgcn_ds_bpermute(sidx, __builtin_bit_cast(int, qhp[2]));
        ai.w = __builtin_amdgcn_ds_bpermute(sidx, __builtin_bit_cast(int, qhp[3]));
        af = __builtin_bit_cast(half8, ai);
    }
    f32x4 acc[4];
#pragma unroll
    for (int ct = 0; ct < 4; ++ct) {
#pragma unroll
        for (int r = 0; r < 4; ++r)
            acc[ct][r] = (float)(*(const _Float16*)&pb_s[w * 16 + q4 + r][ct * 16 + fr]);
    }
#pragma unroll
    for (int ct = 0; ct < 4; ++ct) {
        const int tok = ct * 16 + fr;
        const half8 bf = *(const half8*)&kvp[(size_t)(tok * 8 + (cn ^ (tok & 7))) * 8];
        acc[ct] = __builtin_amdgcn_mfma_f32_16x16x32_f16(af, bf, acc[ct], 0, 0, 0);
    }

    // ---- pool softmax in C-layout (rows q4+r, cols ct*16+fr) ----
#pragma unroll
    for (int r = 0; r < 4; ++r) {
        float mm = fmaxf(fmaxf(acc[0][r], acc[1][r]), fmaxf(acc[2][r], acc[3][r]));
        mm = max16f(mm);
        float z = 0.f;
        float pv[4];
#pragma unroll
        for (int ct = 0; ct < 4; ++ct) {
            pv[ct] = __expf(acc[ct][r] - mm);
            z += pv[ct];
        }
        z = sum16f(z);
#pragma unroll
        for (int ct = 0; ct < 4; ++ct)
            Ps[w * 16 + q4 + r][ct * 16 + fr] = f2h(pv[ct]);
        if (fr == 0) { mzp[w * 16 + q4 + r][0] = mm; mzp[w * 16 + q4 + r][1] = z; }
    }
    // rows written/read by the same wave -> lgkmcnt ordering suffices

    // ---- merge + AV (quad layout) ----
    const float m_p = mzp[j][0];
    const float Z_p = mzp[j][1];
    const float m = fmaxf(m_l, m_p);
    const float fp = __expf(m_p - m);
    float Z = Z_p * fp;
    const _Float16 fh = (_Float16)fp;

    half2_t oh[4];
#pragma unroll
    for (int c = 0; c < 4; ++c) oh[c] = half2_t{(_Float16)0.f, (_Float16)0.f};

#pragma unroll
    for (int cch = 0; cch < 8; ++cch) {
        const half8 p8 = *(const half8*)&Ps[j][cch * 8];
#pragma unroll
        for (int k = 0; k < 8; ++k) {
            const int p = cch * 8 + k;
            const _Float16 ah = p8[k] * fh;
            const half2_t a2 = half2_t{ah, ah};
            const half8 v8 = *(const half8*)
                &kvp[(size_t)(p * 8 + ((4 + g4) ^ (p & 7))) * 8];
            oh[0] = a2 * __builtin_shufflevector(v8, v8, 0, 1) + oh[0];
            oh[1] = a2 * __builtin_shufflevector(v8, v8, 2, 3) + oh[1];
            oh[2] = a2 * __builtin_shufflevector(v8, v8, 4, 5) + oh[2];
            oh[3] = a2 * __builtin_shufflevector(v8, v8, 6, 7) + oh[3];
        }
    }

    // ---- local exps with final m ----
#pragma unroll
    for (int l = 0; l < 9; ++l) { sl[l] = __expf(sl[l] - m); Z += sl[l]; }

    // ---- local AV from LDS: coef = el + lt*Z (final *invZ) ----
#pragma unroll
    for (int l = 0; l < 9; ++l) {
        const int di = l / 3 - 1, dj = l % 3 - 1;
        const int ii = i + di;
        const int jn = j + dj;
        const bool ok = (ii >= 0) && (ii < 64) && (jn >= 0) && (jn < 64);
        const int dr = di + 1;
        const int tokc = max(min(jn, 63), 0);
        const float coef = ok ? (sl[l] + lt[l] * Z) : 0.f;
        const half8 v8 = *(const half8*)
            &kvloc[(size_t)((dr * 64 + tokc) * 8 + ((4 + g4) ^ (tokc & 7))) * 8];
        const _Float16 ch = (_Float16)coef;
        const half2_t c2 = half2_t{ch, ch};
        oh[0] = c2 * __builtin_shufflevector(v8, v8, 0, 1) + oh[0];
        oh[1] = c2 * __builtin_shufflevector(v8, v8, 2, 3) + oh[1];
        oh[2] = c2 * __builtin_shufflevector(v8, v8, 4, 5) + oh[2];
        oh[3] = c2 * __builtin_shufflevector(v8, v8, 6, 7) + oh[3];
    }

    // ---- normalize and store fp16 (head-major, coalesced) ----
    const float invZ = 1.0f / Z;
    ushort4* outp = (ushort4*)(attno + ((size_t)h * Mtot + gq) * 32 + co);
#pragma unroll
    for (int c4 = 0; c4 < 2; ++c4) {
        ushort4 u;
        u.x = f2h((float)oh[2*c4+0][0] * invZ);
        u.y = f2h((float)oh[2*c4+0][1] * invZ);
        u.z = f2h((float)oh[2*c4+1][0] * invZ);
        u.w = f2h((float)oh[2*c4+1][1] * invZ);
        outp[c4] = u;
    }
}

extern "C" void kernel_launch(void* const* d_in, const int* in_sizes, int n_in,
                              void* d_out, int out_size, void* d_ws, size_t ws_size,
                              hipStream_t stream)
{
    const float* x    = (const float*)d_in[0];
    const float* tbl  = (const float*)d_in[1];
    const float* sls  = (const float*)d_in[2];
    const float* q_w  = (const float*)d_in[3];
    const float* q_b  = (const float*)d_in[4];
    const float* kv_w = (const float*)d_in[5];
    const float* kv_b = (const float*)d_in[6];
    const float* temp = (const float*)d_in[7];
    const float* qe   = (const float*)d_in[8];
    const float* sr_w = (const float*)d_in[9];
    const float* sr_b = (const float*)d_in[10];
    const float* ng   = (const float*)d_in[11];
    const float* nb   = (const float*)d_in[12];
    const float* f1w  = (const float*)d_in[13];
    const float* f1b  = (const float*)d_in[14];
    const float* f2w  = (const float*)d_in[15];
    const float* f2b  = (const float*)d_in[16];
    const float* rbl  = (const float*)d_in[17];
    const float* ltok = (const float*)d_in[18];
    const float* lbias= (const float*)d_in[19];
    const float* pw   = (const float*)d_in[20];
    const float* pb   = (const float*)d_in[21];
    const int*   rpi  = (const int*)d_in[22];

    const int C = 256, Hh = 64, Ww = 64, Nn = Hh * Ww;
    const int B = in_sizes[0] / (Nn * C);   // 4
    const int T = in_sizes[1] / 2;
    const int M = B * Nn;                   // 16384

    float* ws = (float*)d_ws;
    size_t o = 0;
    ushort_t* qh    = (ushort_t*)(ws + o); o += (size_t)M * C / 2;     // fp16 (8,M,32)
    ushort_t* kvh   = (ushort_t*)(ws + o); o += (size_t)M * C;         // fp16 (8,M,64)
    ushort_t* xsrh  = (ushort_t*)(ws + o); o += (size_t)M * C / 2;     // fp16 xsr (M,256)
    ushort_t* xpoolh= (ushort_t*)(ws + o); o += (size_t)B * 64 * C / 2;// fp16 x_pool
    ushort_t* kvph  = (ushort_t*)(ws + o); o += (size_t)B * 64 * C;    // fp16 (8,256,64)
    ushort_t* cpbT  = (ushort_t*)(ws + o); o += (size_t)T * 4 + 4;     // fp16 (8,T)
    ushort_t* rpi16 = (ushort_t*)(ws + o); o += 131072;                // ushort (N*64)
    ushort_t* xh   = (ushort_t*)(ws + o); o += (size_t)M * C / 2;      // fp16 x; reused as attno
    ushort_t* Wall = (ushort_t*)(ws + o); o += 1024 * 256 / 2;
    ushort_t* Pwh  = (ushort_t*)(ws + o); o += 256 * 256 / 2;
    float* ball = ws + o; o += 1024;
    ushort_t* attno_hf = xh;   // xh dead after the x-GEMM; (8,M,32)

    dim3 blk(256);
    const int n4x = M * C / 4;
    const int nprep = (n4x + 255) / 256;    // 4096
    const int ncpb  = (T + 3) / 4;

    // prep (cast x + pack weights + rpi16) + cpb MLP (fp16 transposed)
    prep_cpb<<<nprep + ncpb, blk, 0, stream>>>(
        (const float4*)x, (ushort4*)xh, n4x,
        nprep, q_w, kv_w, sr_w, pw, q_b, kv_b, sr_b, rpi, rpi16,
        Wall, Pwh, ball, tbl, f1w, f1b, f2w, f2b, cpbT, T);
    // fused [q | k(norm) | v | sr(gelu)] fp16 GEMM, 128x64 tile, depth-3
    mfma_hgemm<128, 64, false><<<dim3(16, M / 128), blk, 0, stream>>>(
        xh, Wall, ball, nullptr, qh, kvh, xsrh, 0, M);
    // pool + LN (fp16 out)
    pool_ln<<<B * 64, blk, 0, stream>>>(xsrh, ng, nb, xpoolh, Hh, Ww);
    // kv_p fp16 MFMA GEMM with fused k_pool head-norm (head-major out)
    mfma_hgemm<64, 64, false><<<dim3(8, (B * 64) / 64), blk, 0, stream>>>(
        xpoolh, Wall + 256 * 256, ball + 256, nullptr, nullptr, kvph, nullptr, 2, B * 64);
    // attention (head-major in/out; MFMA pool scores; L1-resident bias gather)
    attn_v11<<<dim3(64, 8, B), blk, 0, stream>>>(
        qh, kvh, kvph, rpi16, cpbT, sls, temp, qe, rbl, ltok, lbias, attno_hf, M, T);
    // proj fp16 GEMM <64,64>; A = attno head-major
    mfma_hgemm<64, 64, true><<<dim3(4, M / 64), blk, 0, stream>>>(
        attno_hf, Pwh, pb, (float*)d_out, nullptr, nullptr, nullptr, 1, M);
}

// Round 8
// 208.028 us; speedup vs baseline: 1.1001x; 1.0192x over previous
//
#include <hip/hip_runtime.h>
#include <math.h>

// ---------------------------------------------------------------------------
// TransNeXt aggregated attention. Round 19:
//  - attn_v12: OCCUPANCY round. kvloc LDS staging dropped (local k|v read
//    direct from head-major global: 36KB block working set, L1/L2-hot;
//    R4 showed staging was worth only ~2us). Ps overlaid onto pb_s
//    (wave-private rows: pb read into acc before P written). LDS 52->19KB,
//    3 -> 5-6 blocks/CU.
//  - GEMMs back to depth-2 counted-vmcnt (24KB LDS -> 6 blocks/CU; R7's
//    depth-3 cost occupancy 6->4 for zero net gain).
//  - prep: weight/rpi packing vectorized (float4/int4 -> ushort4).
//  6 dispatches.
// B=4, H=W=64, C=256, NH=8, hd=32, LOCAL_LEN=9, pool 8x8=64
// ---------------------------------------------------------------------------

typedef unsigned short ushort_t;
typedef __attribute__((ext_vector_type(8))) _Float16 half8;
typedef __attribute__((ext_vector_type(2))) _Float16 half2_t;
typedef __attribute__((ext_vector_type(4))) float f32x4;
typedef __attribute__((ext_vector_type(4))) int int4_t;

static __device__ __forceinline__ ushort_t f2h(float f) {
    _Float16 h = (_Float16)f;           // RTNE
    return *(ushort_t*)&h;
}

static __device__ __forceinline__ float fdot2f(half2_t a, half2_t b, float c) {
#if __has_builtin(__builtin_amdgcn_fdot2)
    return __builtin_amdgcn_fdot2(a, b, c, false);
#else
    return (float)a[0] * (float)b[0] + (float)a[1] * (float)b[1] + c;
#endif
}

// ---- DPP lane reductions (VALU pipe) --------------------------------------
template <int CTRL>
static __device__ __forceinline__ float dpp_addf(float x) {
    int v = __builtin_amdgcn_update_dpp(
        0, __builtin_bit_cast(int, x), CTRL, 0xF, 0xF, true);
    return x + __builtin_bit_cast(float, v);
}
template <int CTRL>
static __device__ __forceinline__ float dpp_maxf(float x) {
    int v = __builtin_amdgcn_update_dpp(
        0, __builtin_bit_cast(int, x), CTRL, 0xF, 0xF, true);
    return fmaxf(x, __builtin_bit_cast(float, v));
}
static __device__ __forceinline__ float quad_sumf(float x) {
    return dpp_addf<0x4E>(dpp_addf<0xB1>(x));
}
static __device__ __forceinline__ float sum16f(float x) {
    return dpp_addf<0x128>(dpp_addf<0x124>(quad_sumf(x)));
}
static __device__ __forceinline__ float max16f(float x) {
    return dpp_maxf<0x128>(dpp_maxf<0x124>(dpp_maxf<0x4E>(dpp_maxf<0xB1>(x))));
}

#define GLOAD16(g, l)                                                        \
    __builtin_amdgcn_global_load_lds(                                        \
        (const __attribute__((address_space(1))) unsigned int*)(g),          \
        (__attribute__((address_space(3))) unsigned int*)(l), 16, 0, 0)

// ---------------------------------------------------------------------------
// mfma_hgemm<TM,TN,AHM>: C = A @ W^T + bias, fp16 in, fp32 accum.
// 4 waves 2x2; depth-2 counted-vmcnt pipeline (R14/R5 proven config);
// LDS XOR-swizzle. AHM: A head-major (8, Arows, 32), one head per BK=32.
// mode 0: qh (8,M,32) | kvh k normed (8,M,64) | kvh v | gelu -> xsrh (M,256)
// mode 1 (proj, N=256): out0 fp32 (M,256)
// mode 2 (kv_p, N=512): kvph (8,Arows,64), k normed
// ---------------------------------------------------------------------------
template <int TM, int TN, bool AHM>
__global__ __launch_bounds__(256) void mfma_hgemm(
    const ushort_t* __restrict__ Ag, const ushort_t* __restrict__ Bg,
    const float* __restrict__ bias, float* __restrict__ out0,
    ushort_t* __restrict__ qh_out, ushort_t* __restrict__ kvh,
    ushort_t* __restrict__ xsrh, int mode, int Arows)
{
    const int K = 256;
    const int IM = TM / 32;
    const int JN = TN / 32;
    constexpr int LPS = TM / 64 + TN / 64;
    __shared__ ushort_t Ah[2][TM * 32];
    __shared__ ushort_t Bh[2][TN * 32];

    const int t = threadIdx.x;
    const int w = t >> 6;
    const int lane = t & 63;

    // XCD-aware bijective chunk swizzle (all grids are %8 == 0)
    const int nwg = gridDim.x * gridDim.y;
    int wg = blockIdx.y * gridDim.x + blockIdx.x;
    wg = (wg & 7) * (nwg >> 3) + (wg >> 3);
    const int bm = (wg / gridDim.x) * TM;
    const int bn = (wg % gridDim.x) * TN;

    const int wm = (w >> 1) * (TM / 2);
    const int wn = (w & 1) * (TN / 2);

    f32x4 acc[IM][JN];
#pragma unroll
    for (int i = 0; i < IM; ++i)
#pragma unroll
        for (int j = 0; j < JN; ++j) acc[i][j] = f32x4{0.f, 0.f, 0.f, 0.f};

    const int lrow  = t >> 2;
    const int lk8sw = ((t & 3) ^ ((t >> 3) & 3)) * 8;  // pre-swizzled src col

#define STAGE(bufi, k0s)                                                     \
    do {                                                                     \
        _Pragma("unroll")                                                    \
        for (int r = 0; r < TM / 64; ++r) {                                  \
            const ushort_t* srcA = AHM                                       \
                ? Ag + ((size_t)((k0s) >> 5) * Arows + (bm + r * 64 + lrow)) * 32 + lk8sw \
                : Ag + (size_t)(bm + r * 64 + lrow) * K + (k0s) + lk8sw;     \
            GLOAD16(srcA, &Ah[bufi][(unsigned)(r * 64 + w * 16) * 32]);      \
        }                                                                    \
        _Pragma("unroll")                                                    \
        for (int r = 0; r < TN / 64; ++r)                                    \
            GLOAD16(Bg + (size_t)(bn + r * 64 + lrow) * K + (k0s) + lk8sw,   \
                    &Bh[bufi][(unsigned)(r * 64 + w * 16) * 32]);            \
    } while (0)

    const int fr   = lane & 15;
    const int sws8 = ((lane >> 4) ^ ((fr >> 1) & 3)) * 8;  // swizzled read slot

#define COMPUTE(bufi)                                                        \
    do {                                                                     \
        half8 af[IM], bf[JN];                                                \
        _Pragma("unroll")                                                    \
        for (int i2 = 0; i2 < IM; ++i2)                                      \
            af[i2] = *(const half8*)&Ah[bufi][(unsigned)(wm + i2 * 16 + fr) * 32 + sws8]; \
        _Pragma("unroll")                                                    \
        for (int j2 = 0; j2 < JN; ++j2)                                      \
            bf[j2] = *(const half8*)&Bh[bufi][(unsigned)(wn + j2 * 16 + fr) * 32 + sws8]; \
        __builtin_amdgcn_s_setprio(1);                                       \
        _Pragma("unroll")                                                    \
        for (int i2 = 0; i2 < IM; ++i2)                                      \
            _Pragma("unroll")                                                \
            for (int j2 = 0; j2 < JN; ++j2)                                  \
                acc[i2][j2] = __builtin_amdgcn_mfma_f32_16x16x32_f16(        \
                    af[i2], bf[j2], acc[i2][j2], 0, 0, 0);                   \
        __builtin_amdgcn_s_setprio(0);                                       \
    } while (0)

    STAGE(0, 0);
    STAGE(1, 32);
    int buf = 0;
#pragma unroll
    for (int s = 0; s < K / 32 - 1; ++s) {
        asm volatile("s_waitcnt vmcnt(%0)" :: "n"(LPS) : "memory");
        __builtin_amdgcn_s_barrier();
        asm volatile("" ::: "memory");
        COMPUTE(buf);
        asm volatile("" ::: "memory");
        __builtin_amdgcn_s_barrier();
        asm volatile("" ::: "memory");
        if (s + 2 < K / 32) STAGE(buf, (s + 2) * 32);
        buf ^= 1;
    }
    asm volatile("s_waitcnt vmcnt(0)" ::: "memory");
    __builtin_amdgcn_s_barrier();
    asm volatile("" ::: "memory");
    COMPUTE(buf);
#undef COMPUTE
#undef STAGE

    // epilogue: C/D layout col=lane&15, row=(lane>>4)*4+reg.
    const int q4 = (lane >> 4) * 4;
#pragma unroll
    for (int i = 0; i < IM; ++i) {
#pragma unroll
        for (int jp = 0; jp < JN / 2; ++jp) {
#pragma unroll
            for (int r = 0; r < 4; ++r) {
                const int row = bm + wm + i * 16 + q4 + r;
                const int col0 = bn + wn + jp * 32 + fr;
                const int col1 = col0 + 16;
                float v0 = acc[i][2 * jp][r] + bias[col0];
                float v1 = acc[i][2 * jp + 1][r] + bias[col1];
                if (mode == 0) {
                    if (col0 < 256) {
                        const size_t base = ((size_t)(col0 >> 5) * Arows + row) * 32;
                        qh_out[base + fr]      = f2h(v0);
                        qh_out[base + fr + 16] = f2h(v1);
                    } else if (col0 < 512) {   // k: fused per-head L2 norm
                        const float ss = sum16f(v0 * v0 + v1 * v1);
                        const float invn = 1.0f / fmaxf(sqrtf(ss), 1e-12f);
                        const size_t base = ((size_t)((col0 - 256) >> 5) * Arows + row) * 64;
                        kvh[base + fr]      = f2h(v0 * invn);
                        kvh[base + fr + 16] = f2h(v1 * invn);
                    } else if (col0 < 768) {   // v
                        const size_t base = ((size_t)((col0 - 512) >> 5) * Arows + row) * 64 + 32;
                        kvh[base + fr]      = f2h(v0);
                        kvh[base + fr + 16] = f2h(v1);
                    } else {                    // sr + gelu (row-major kept)
                        v0 = 0.5f * v0 * (1.0f + erff(v0 * 0.70710678118654752f));
                        v1 = 0.5f * v1 * (1.0f + erff(v1 * 0.70710678118654752f));
                        xsrh[(size_t)row * 256 + (col0 - 768)] = f2h(v0);
                        xsrh[(size_t)row * 256 + (col1 - 768)] = f2h(v1);
                    }
                } else if (mode == 2) {         // kv_p head-major
                    if (col0 < 256) {           // k_pool: fused per-head norm
                        const float ss = sum16f(v0 * v0 + v1 * v1);
                        const float invn = 1.0f / fmaxf(sqrtf(ss), 1e-12f);
                        const size_t base = ((size_t)(col0 >> 5) * Arows + row) * 64;
                        kvh[base + fr]      = f2h(v0 * invn);
                        kvh[base + fr + 16] = f2h(v1 * invn);
                    } else {
                        const size_t base = ((size_t)((col0 - 256) >> 5) * Arows + row) * 64 + 32;
                        kvh[base + fr]      = f2h(v0);
                        kvh[base + fr + 16] = f2h(v1);
                    }
                } else {
                    out0[(size_t)row * 256 + col0] = v0;
                    out0[(size_t)row * 256 + col1] = v1;
                }
            }
        }
    }
}

// prep_cpb: x cast + vectorized weight/rpi packing + cpb MLP (fp16,
// transposed per-head) in one kernel.
__global__ __launch_bounds__(256) void prep_cpb(
    const float4* __restrict__ x, ushort4* __restrict__ xh, int n4, int nprep,
    const float* __restrict__ qw, const float* __restrict__ kvw,
    const float* __restrict__ srw, const float* __restrict__ pw,
    const float* __restrict__ qb, const float* __restrict__ kvb,
    const float* __restrict__ srb,
    const int* __restrict__ rpi, ushort_t* __restrict__ rpi16,
    ushort_t* __restrict__ Wall, ushort_t* __restrict__ Pw,
    float* __restrict__ ball,
    const float* __restrict__ table, const float* __restrict__ w1,
    const float* __restrict__ b1, const float* __restrict__ w2,
    const float* __restrict__ b2, ushort_t* __restrict__ cpbT, int T)
{
    if (blockIdx.x >= nprep) {
        const int wv = threadIdx.x >> 6;
        const int lane = threadIdx.x & 63;
        const int row = (blockIdx.x - nprep) * 4 + wv;
        if (row >= T) return;
        const float t0 = table[(size_t)row * 2];
        const float t1 = table[(size_t)row * 2 + 1];
        const int base = lane * 8;

        const float4* w1p = (const float4*)(w1 + (size_t)base * 2);
        float4 wa = w1p[0], wb = w1p[1], wc = w1p[2], wd = w1p[3];
        float4 ba = *(const float4*)(b1 + base);
        float4 bb = *(const float4*)(b1 + base + 4);
        float h[8];
        h[0] = fmaxf(fmaf(t1, wa.y, fmaf(t0, wa.x, ba.x)), 0.f);
        h[1] = fmaxf(fmaf(t1, wa.w, fmaf(t0, wa.z, ba.y)), 0.f);
        h[2] = fmaxf(fmaf(t1, wb.y, fmaf(t0, wb.x, ba.z)), 0.f);
        h[3] = fmaxf(fmaf(t1, wb.w, fmaf(t0, wb.z, ba.w)), 0.f);
        h[4] = fmaxf(fmaf(t1, wc.y, fmaf(t0, wc.x, bb.x)), 0.f);
        h[5] = fmaxf(fmaf(t1, wc.w, fmaf(t0, wc.z, bb.y)), 0.f);
        h[6] = fmaxf(fmaf(t1, wd.y, fmaf(t0, wd.x, bb.z)), 0.f);
        h[7] = fmaxf(fmaf(t1, wd.w, fmaf(t0, wd.z, bb.w)), 0.f);

#pragma unroll
        for (int hh = 0; hh < 8; ++hh) {
            const float4* w2p = (const float4*)(w2 + (size_t)hh * 512 + base);
            float4 p0 = w2p[0], p1 = w2p[1];
            float s = h[0]*p0.x + h[1]*p0.y + h[2]*p0.z + h[3]*p0.w
                    + h[4]*p1.x + h[5]*p1.y + h[6]*p1.z + h[7]*p1.w;
#pragma unroll
            for (int off = 1; off <= 32; off <<= 1) s += __shfl_xor(s, off);
            if (lane == 0) cpbT[(size_t)hh * T + row] = f2h(s + b2[hh]);
        }
        return;
    }

    int idx = blockIdx.x * 256 + threadIdx.x;
    if (idx < n4) {
        float4 v = x[idx];
        ushort4 h;
        h.x = f2h(v.x); h.y = f2h(v.y); h.z = f2h(v.z); h.w = f2h(v.w);
        xh[idx] = h;
    }
    if (idx < 65536) {                       // weights + rpi, 4 elems/thread
        const int base = idx * 4;
        const int nn = base >> 8, k = base & 255;
        const float* src;
        if (nn < 256)      src = qw + (size_t)nn * 256 + k;
        else if (nn < 768) src = kvw + (size_t)(nn - 256) * 256 + k;
        else               src = srw + (size_t)(nn - 768) * 256 + k;
        const float4 a = *(const float4*)src;
        ushort4 hw;
        hw.x = f2h(a.x); hw.y = f2h(a.y); hw.z = f2h(a.z); hw.w = f2h(a.w);
        *(ushort4*)&Wall[base] = hw;
        const int4 rv = *(const int4*)&rpi[base];
        ushort4 r4;
        r4.x = (ushort_t)rv.x; r4.y = (ushort_t)rv.y;
        r4.z = (ushort_t)rv.z; r4.w = (ushort_t)rv.w;
        *(ushort4*)&rpi16[base] = r4;
    }
    if (idx < 16384) {                       // proj weights, 4 elems/thread
        const float4 a = *(const float4*)&pw[(size_t)idx * 4];
        ushort4 hw;
        hw.x = f2h(a.x); hw.y = f2h(a.y); hw.z = f2h(a.z); hw.w = f2h(a.w);
        *(ushort4*)&Pw[(size_t)idx * 4] = hw;
    }
    if (idx < 1024) {
        float bv;
        if (idx < 256)      bv = qb[idx];
        else if (idx < 768) bv = kvb[idx - 256];
        else                bv = srb[idx - 768];
        ball[idx] = bv;
    }
}

// 8x8 average pool of x_sr fp16 (B,N,C) + LayerNorm -> xpool fp16 (B,64,C)
__global__ __launch_bounds__(256) void pool_ln(
    const ushort_t* __restrict__ xsr, const float* __restrict__ g,
    const float* __restrict__ be, ushort_t* __restrict__ xpool, int Hh, int Ww)
{
    const int C = 256;
    const int Nn = Hh * Ww;
    int b = blockIdx.x >> 6;
    int pidx = blockIdx.x & 63;
    int ph = pidx >> 3, pw = pidx & 7;
    int tid = threadIdx.x;
    float s = 0.f;
    for (int si = 0; si < 8; ++si) {
        int i = ph * 8 + si;
        const ushort_t* rowp = xsr + ((size_t)b * Nn + (size_t)i * Ww + pw * 8) * C + tid;
#pragma unroll
        for (int sj = 0; sj < 8; ++sj)
            s += (float)(*(const _Float16*)&rowp[(size_t)sj * C]);
    }
    s *= (1.f / 64.f);
    __shared__ float red[256];
    red[tid] = s; __syncthreads();
    for (int st = 128; st; st >>= 1) { if (tid < st) red[tid] += red[tid + st]; __syncthreads(); }
    float mean = red[0] * (1.f / 256.f);
    __syncthreads();
    float dv = s - mean;
    red[tid] = dv * dv; __syncthreads();
    for (int st = 128; st; st >>= 1) { if (tid < st) red[tid] += red[tid + st]; __syncthreads(); }
    float var = red[0] * (1.f / 256.f);
    xpool[(size_t)blockIdx.x * C + tid] = f2h(dv * rsqrtf(var + 1e-5f) * g[tid] + be[tid]);
}

// ---------------------------------------------------------------------------
// attn_v12: LOW-LDS variant. Local k|v read direct from head-major global
// (L1/L2-hot); pool k|v in LDS; pb_s and exp'd-P share one buffer
// (wave-private rows: pb consumed into acc before P written).
// LDS ~19KB -> 5-6 blocks/CU (was 52KB -> 3).
// ---------------------------------------------------------------------------
__global__ __launch_bounds__(256) void attn_v12(
    const ushort_t* __restrict__ qh_g, // (8,M,32) fp16 raw q
    const ushort_t* __restrict__ kvh,  // (8,M,64) fp16 {k normed | v}
    const ushort_t* __restrict__ kvph, // (8,256,64) fp16 {k_pool normed | v_pool}
    const ushort_t* __restrict__ rpi16,// (N*64) table index (ushort)
    const ushort_t* __restrict__ cpbT, // (8,T) fp16 cpb, per-head
    const float* __restrict__ sls, const float* __restrict__ temp,
    const float* __restrict__ qe, const float* __restrict__ rbl,
    const float* __restrict__ ltok, const float* __restrict__ lbias,
    ushort_t* __restrict__ attno,      // (8,M,32) fp16
    int Mtot, int T)
{
    const int h = blockIdx.y, b = blockIdx.z;
    const int t = threadIdx.x;
    const int i = blockIdx.x;
    const int w = t >> 6;
    const int lane = t & 63;

    __shared__ ushort_t kvp[64 * 64];   // pool k|v (8KB); chunk ^= (tok&7)
    __shared__ ushort_t pbPs[64][72];   // pool bias -> overlaid exp'd P (9KB)
    __shared__ float mzp[64][2];
    __shared__ float lts[9][32];
    __shared__ float rbl_s[9], lb_s[9], qe_s[32];

    // ---- async stage of pool k|v ----
    {
        const int lt8 = lane >> 3, ls = lane & 7;
#pragma unroll
        for (int it = 0; it < 2; ++it) {
            const int u = it * 4 + w;            // 0..7
            const int tok = u * 8 + lt8;
            GLOAD16(kvph + ((size_t)h * 256 + b * 64) * 64
                         + (size_t)(tok * 8 + (ls ^ (tok & 7))) * 8,
                    &kvp[(size_t)(u * 8) * 64]);
        }
    }
    // ---- pb gather + tables (overlaps async stage latency) ----
    {
        const ushort_t* rp16 = rpi16 + (size_t)i * 4096;
        const ushort_t* ctab = cpbT + (size_t)h * T;
        for (int u = t; u < 4096; u += 256)
            pbPs[u >> 6][u & 63] = ctab[rp16[u]];
        for (int u = t; u < 288; u += 256) lts[u % 9][u / 9] = ltok[h * 288 + u];
        if (t < 9)  { rbl_s[t] = rbl[h * 9 + t]; lb_s[t] = lbias[h * 9 + t]; }
        if (t >= 64 && t < 96) qe_s[t - 64] = qe[h * 32 + (t - 64)];
    }
    __syncthreads();

    const int qi = lane >> 2;
    const int g4 = lane & 3;
    const int co = g4 * 8;
    const int j = w * 16 + qi;
    const int n = i * 64 + j;
    const size_t gq = (size_t)b * 4096 + n;
    const ushort_t* kvb = kvh + ((size_t)h * Mtot + (size_t)b * 4096) * 64;

    const float tm = temp[h];
    const float sp = (tm > 20.f) ? tm : log1pf(expf(tm));

    // ---- load q slice (head-major), L2-normalize (quad DPP reduce) ----
    float qv[8];
    {
        const half8 q8 = *(const half8*)(qh_g + ((size_t)h * Mtot + gq) * 32 + co);
        float ss = 0.f;
#pragma unroll
        for (int d = 0; d < 8; ++d) { qv[d] = (float)q8[d]; ss += qv[d] * qv[d]; }
        ss = quad_sumf(ss);
        const float invn = 1.0f / fmaxf(sqrtf(ss), 1e-12f);
#pragma unroll
        for (int d = 0; d < 8; ++d) qv[d] *= invn;
    }

    // ---- learnable-token dots (fp32) ----
    float lt[9];
#pragma unroll
    for (int l = 0; l < 9; ++l) {
        float dl = 0.f;
        const float4* lw = (const float4*)&lts[l][co];
#pragma unroll
        for (int c4 = 0; c4 < 2; ++c4) {
            float4 w4 = lw[c4];
            dl += qv[4*c4+0]*w4.x + qv[4*c4+1]*w4.y + qv[4*c4+2]*w4.z + qv[4*c4+3]*w4.w;
        }
        dl = quad_sumf(dl);
        lt[l] = dl + lb_s[l];
    }

    // ---- scaled q -> fp16 pairs (quad layout) ----
    const float scal = sp * sls[n];
    half2_t qhp[4];
#pragma unroll
    for (int c = 0; c < 4; ++c) {
        float a = (qv[2*c+0] + qe_s[co + 2*c+0]) * scal;
        float bq = (qv[2*c+1] + qe_s[co + 2*c+1]) * scal;
        qhp[c] = half2_t{(_Float16)a, (_Float16)bq};
    }

    // ---- local scores (k direct from global, head-major) ----
    float sl[9];
#pragma unroll
    for (int l = 0; l < 9; ++l) {
        const int di = l / 3 - 1, dj = l % 3 - 1;
        const int ii = i + di;
        const int jn = j + dj;
        const bool ok = (ii >= 0) && (ii < 64) && (jn >= 0) && (jn < 64);
        const int ic = max(min(ii, 63), 0);
        const int jc = max(min(jn, 63), 0);
        const half8 k8 = *(const half8*)&kvb[(size_t)(ic * 64 + jc) * 64 + co];
        float dk = 0.f;
        dk = fdot2f(qhp[0], __builtin_shufflevector(k8, k8, 0, 1), dk);
        dk = fdot2f(qhp[1], __builtin_shufflevector(k8, k8, 2, 3), dk);
        dk = fdot2f(qhp[2], __builtin_shufflevector(k8, k8, 4, 5), dk);
        dk = fdot2f(qhp[3], __builtin_shufflevector(k8, k8, 6, 7), dk);
        dk = quad_sumf(dk);
        sl[l] = ok ? (dk + rbl_s[l]) : -INFINITY;
    }
    float m_l = sl[0];
#pragma unroll
    for (int l = 1; l < 9; ++l) m_l = fmaxf(m_l, sl[l]);

    // ---- pool scores via MFMA -------------------------------------------
    const int fr = lane & 15;
    const int cn = lane >> 4;           // k-chunk / reg-group
    const int q4 = cn * 4;
    half8 af;
    {
        const int sidx = (4 * fr + cn) << 2;
        int4_t ai;
        ai.x = __builtin_amdgcn_ds_bpermute(sidx, __builtin_bit_cast(int, qhp[0]));
        ai.y = __builtin_amdgcn_ds_bpermute(sidx, __builtin_bit_cast(int, qhp[1]));
        ai.z = __builtin_amdgcn_ds_bpermute(sidx, __builtin_bit_cast(int, qhp[2]));
        ai.w = __builtin_amdgcn_ds_bpermute(sidx, __builtin_bit_cast(int, qhp[3]));
        af = __builtin_bit_cast(half8, ai);
    }
    f32x4 acc[4];
#pragma unroll
    for (int ct = 0; ct < 4; ++ct) {
        // bias preload from pbPs (consumed BEFORE the same rows get P)
#pragma unroll
        for (int r = 0; r < 4; ++r)
            acc[ct][r] = (float)(*(const _Float16*)&pbPs[w * 16 + q4 + r][ct * 16 + fr]);
    }
#pragma unroll
    for (int ct = 0; ct < 4; ++ct) {
        const int tok = ct * 16 + fr;
        const half8 bf = *(const half8*)&kvp[(size_t)(tok * 8 + (cn ^ (tok & 7))) * 8];
        acc[ct] = __builtin_amdgcn_mfma_f32_16x16x32_f16(af, bf, acc[ct], 0, 0, 0);
    }

    // ---- pool softmax in C-layout; exp'd P overlaid into pbPs ----
#pragma unroll
    for (int r = 0; r < 4; ++r) {
        float mm = fmaxf(fmaxf(acc[0][r], acc[1][r]), fmaxf(acc[2][r], acc[3][r]));
        mm = max16f(mm);
        float z = 0.f;
        float pv[4];
#pragma unroll
        for (int ct = 0; ct < 4; ++ct) {
            pv[ct] = __expf(acc[ct][r] - mm);
            z += pv[ct];
        }
        z = sum16f(z);
#pragma unroll
        for (int ct = 0; ct < 4; ++ct)
            pbPs[w * 16 + q4 + r][ct * 16 + fr] = f2h(pv[ct]);
        if (fr == 0) { mzp[w * 16 + q4 + r][0] = mm; mzp[w * 16 + q4 + r][1] = z; }
    }
    // rows written/read by the same wave -> lgkmcnt ordering suffices

    // ---- merge + AV (quad layout) ----
    const float m_p = mzp[j][0];
    const float Z_p = mzp[j][1];
    const float m = fmaxf(m_l, m_p);
    const float fp = __expf(m_p - m);
    float Z = Z_p * fp;
    const _Float16 fh = (_Float16)fp;

    half2_t oh[4];
#pragma unroll
    for (int c = 0; c < 4; ++c) oh[c] = half2_t{(_Float16)0.f, (_Float16)0.f};

#pragma unroll
    for (int cch = 0; cch < 8; ++cch) {
        const half8 p8 = *(const half8*)&pbPs[j][cch * 8];
#pragma unroll
        for (int k = 0; k < 8; ++k) {
            const int p = cch * 8 + k;
            const _Float16 ah = p8[k] * fh;
            const half2_t a2 = half2_t{ah, ah};
            const half8 v8 = *(const half8*)
                &kvp[(size_t)(p * 8 + ((4 + g4) ^ (p & 7))) * 8];
            oh[0] = a2 * __builtin_shufflevector(v8, v8, 0, 1) + oh[0];
            oh[1] = a2 * __builtin_shufflevector(v8, v8, 2, 3) + oh[1];
            oh[2] = a2 * __builtin_shufflevector(v8, v8, 4, 5) + oh[2];
            oh[3] = a2 * __builtin_shufflevector(v8, v8, 6, 7) + oh[3];
        }
    }

    // ---- local exps with final m ----
#pragma unroll
    for (int l = 0; l < 9; ++l) { sl[l] = __expf(sl[l] - m); Z += sl[l]; }

    // ---- local AV direct from global: coef = el + lt*Z (final *invZ) ----
#pragma unroll
    for (int l = 0; l < 9; ++l) {
        const int di = l / 3 - 1, dj = l % 3 - 1;
        const int ii = i + di;
        const int jn = j + dj;
        const bool ok = (ii >= 0) && (ii < 64) && (jn >= 0) && (jn < 64);
        const int ic = max(min(ii, 63), 0);
        const int jc = max(min(jn, 63), 0);
        const float coef = ok ? (sl[l] + lt[l] * Z) : 0.f;
        const half8 v8 = *(const half8*)&kvb[(size_t)(ic * 64 + jc) * 64 + 32 + co];
        const _Float16 ch = (_Float16)coef;
        const half2_t c2 = half2_t{ch, ch};
        oh[0] = c2 * __builtin_shufflevector(v8, v8, 0, 1) + oh[0];
        oh[1] = c2 * __builtin_shufflevector(v8, v8, 2, 3) + oh[1];
        oh[2] = c2 * __builtin_shufflevector(v8, v8, 4, 5) + oh[2];
        oh[3] = c2 * __builtin_shufflevector(v8, v8, 6, 7) + oh[3];
    }

    // ---- normalize and store fp16 (head-major, coalesced) ----
    const float invZ = 1.0f / Z;
    ushort4* outp = (ushort4*)(attno + ((size_t)h * Mtot + gq) * 32 + co);
#pragma unroll
    for (int c4 = 0; c4 < 2; ++c4) {
        ushort4 u;
        u.x = f2h((float)oh[2*c4+0][0] * invZ);
        u.y = f2h((float)oh[2*c4+0][1] * invZ);
        u.z = f2h((float)oh[2*c4+1][0] * invZ);
        u.w = f2h((float)oh[2*c4+1][1] * invZ);
        outp[c4] = u;
    }
}

extern "C" void kernel_launch(void* const* d_in, const int* in_sizes, int n_in,
                              void* d_out, int out_size, void* d_ws, size_t ws_size,
                              hipStream_t stream)
{
    const float* x    = (const float*)d_in[0];
    const float* tbl  = (const float*)d_in[1];
    const float* sls  = (const float*)d_in[2];
    const float* q_w  = (const float*)d_in[3];
    const float* q_b  = (const float*)d_in[4];
    const float* kv_w = (const float*)d_in[5];
    const float* kv_b = (const float*)d_in[6];
    const float* temp = (const float*)d_in[7];
    const float* qe   = (const float*)d_in[8];
    const float* sr_w = (const float*)d_in[9];
    const float* sr_b = (const float*)d_in[10];
    const float* ng   = (const float*)d_in[11];
    const float* nb   = (const float*)d_in[12];
    const float* f1w  = (const float*)d_in[13];
    const float* f1b  = (const float*)d_in[14];
    const float* f2w  = (const float*)d_in[15];
    const float* f2b  = (const float*)d_in[16];
    const float* rbl  = (const float*)d_in[17];
    const float* ltok = (const float*)d_in[18];
    const float* lbias= (const float*)d_in[19];
    const float* pw   = (const float*)d_in[20];
    const float* pb   = (const float*)d_in[21];
    const int*   rpi  = (const int*)d_in[22];

    const int C = 256, Hh = 64, Ww = 64, Nn = Hh * Ww;
    const int B = in_sizes[0] / (Nn * C);   // 4
    const int T = in_sizes[1] / 2;
    const int M = B * Nn;                   // 16384

    float* ws = (float*)d_ws;
    size_t o = 0;
    ushort_t* qh    = (ushort_t*)(ws + o); o += (size_t)M * C / 2;     // fp16 (8,M,32)
    ushort_t* kvh   = (ushort_t*)(ws + o); o += (size_t)M * C;         // fp16 (8,M,64)
    ushort_t* xsrh  = (ushort_t*)(ws + o); o += (size_t)M * C / 2;     // fp16 xsr (M,256)
    ushort_t* xpoolh= (ushort_t*)(ws + o); o += (size_t)B * 64 * C / 2;// fp16 x_pool
    ushort_t* kvph  = (ushort_t*)(ws + o); o += (size_t)B * 64 * C;    // fp16 (8,256,64)
    ushort_t* cpbT  = (ushort_t*)(ws + o); o += (size_t)T * 4 + 4;     // fp16 (8,T)
    ushort_t* rpi16 = (ushort_t*)(ws + o); o += 131072;                // ushort (N*64)
    ushort_t* xh   = (ushort_t*)(ws + o); o += (size_t)M * C / 2;      // fp16 x; reused as attno
    ushort_t* Wall = (ushort_t*)(ws + o); o += 1024 * 256 / 2;
    ushort_t* Pwh  = (ushort_t*)(ws + o); o += 256 * 256 / 2;
    float* ball = ws + o; o += 1024;
    ushort_t* attno_hf = xh;   // xh dead after the x-GEMM; (8,M,32)

    dim3 blk(256);
    const int n4x = M * C / 4;
    const int nprep = (n4x + 255) / 256;    // 4096
    const int ncpb  = (T + 3) / 4;

    // prep (cast x + vectorized packing) + cpb MLP (fp16 transposed)
    prep_cpb<<<nprep + ncpb, blk, 0, stream>>>(
        (const float4*)x, (ushort4*)xh, n4x,
        nprep, q_w, kv_w, sr_w, pw, q_b, kv_b, sr_b, rpi, rpi16,
        Wall, Pwh, ball, tbl, f1w, f1b, f2w, f2b, cpbT, T);
    // fused [q | k(norm) | v | sr(gelu)] fp16 GEMM, 128x64 tile, depth-2
    mfma_hgemm<128, 64, false><<<dim3(16, M / 128), blk, 0, stream>>>(
        xh, Wall, ball, nullptr, qh, kvh, xsrh, 0, M);
    // pool + LN (fp16 out)
    pool_ln<<<B * 64, blk, 0, stream>>>(xsrh, ng, nb, xpoolh, Hh, Ww);
    // kv_p fp16 MFMA GEMM with fused k_pool head-norm (head-major out)
    mfma_hgemm<64, 64, false><<<dim3(8, (B * 64) / 64), blk, 0, stream>>>(
        xpoolh, Wall + 256 * 256, ball + 256, nullptr, nullptr, kvph, nullptr, 2, B * 64);
    // attention (low-LDS; local k|v direct from global; MFMA pool scores)
    attn_v12<<<dim3(64, 8, B), blk, 0, stream>>>(
        qh, kvh, kvph, rpi16, cpbT, sls, temp, qe, rbl, ltok, lbias, attno_hf, M, T);
    // proj fp16 GEMM <64,64>; A = attno head-major
    mfma_hgemm<64, 64, true><<<dim3(4, M / 64), blk, 0, stream>>>(
        attno_hf, Pwh, pb, (float*)d_out, nullptr, nullptr, nullptr, 1, M);
}